// Round 13
// baseline (122.021 us; speedup 1.0000x reference)
//
#include <hip/hip_runtime.h>
#include <math.h>

#define NS 10
#define NB 32
#define NG 1000
#define NE 128
#define NH 8
#define MSH 16

typedef __bf16 bf16x8 __attribute__((ext_vector_type(8)));
typedef float f32x4 __attribute__((ext_vector_type(4)));
typedef unsigned short ushort;
typedef ushort us8 __attribute__((ext_vector_type(8)));

__device__ __forceinline__ ushort f2bf(float f) {
    union { float f; unsigned u; } c; c.f = f;
    unsigned r = c.u + 0x7FFFu + ((c.u >> 16) & 1u);
    return (ushort)(r >> 16);
}
__device__ __forceinline__ float bflo(unsigned u) {
    union { unsigned v; float f; } c; c.v = u << 16; return c.f;
}
__device__ __forceinline__ float bfhi(unsigned u) {
    union { unsigned v; float f; } c; c.v = u & 0xFFFF0000u; return c.f;
}
__device__ __forceinline__ float asf(int i) {
    union { int i; float f; } c; c.i = i; return c.f;
}
__device__ __forceinline__ int asi(float f) {
    union { float f; int i; } c; c.f = f; return c.i;
}
__device__ __forceinline__ float dot8(uint4 q, uint4 k) {
    return bflo(q.x) * bflo(k.x) + bfhi(q.x) * bfhi(k.x)
         + bflo(q.y) * bflo(k.y) + bfhi(q.y) * bfhi(k.y)
         + bflo(q.z) * bflo(k.z) + bfhi(q.z) * bfhi(k.z)
         + bflo(q.w) * bflo(k.w) + bfhi(q.w) * bfhi(k.w);
}

// ---------------- Kernel A: QK GEMM (blocks<500, 64-row tiles) + scatter + wcvt
// QKb rows: 256 bf16 (Q cols 0-127, K cols 128-255). edge_pack[sb][src] =
// {dst, dist_bits}. B-frags read Wq/Wk f32 directly, convert in-register.
__global__ __launch_bounds__(512) void qk_prep(
        const float* __restrict__ ne,
        const int* __restrict__ sol, const float* __restrict__ dist,
        const float* __restrict__ Wq, const float* __restrict__ Wk,
        const float* __restrict__ wih, const float* __restrict__ whh,
        ushort* __restrict__ QKb, ushort* __restrict__ ne_b,
        int2* __restrict__ edge_pack,
        ushort* __restrict__ wih_b, ushort* __restrict__ whh_b) {
    const int tid = threadIdx.x;
    if (blockIdx.x >= 500) {
        const int bid2 = blockIdx.x - 500;
        if (bid2 < 625) {
            // edge_pack scatter: 625*512 = 320000 edges
            const int gidx = bid2 * 512 + tid;         // (s*NB+b)*NG + t
            const int sb = gidx / NG;
            const int t = gidx - sb * NG;
            const int* srow = sol + (size_t)sb * NG;
            const int src = srow[t];
            const int tn = (t + 1 == NG) ? 0 : t + 1;
            const int dst = srow[tn];
            const int b = sb & 31;                     // NB = 32
            const float ev = dist[(size_t)(b * NG + src) * NG + dst];
            edge_pack[(size_t)sb * NG + src] = make_int2(dst, asi(ev));
        } else {
            const int wt = (bid2 - 625) * 512 + tid;   // 12288 chunk threads
            const int e = wt * 8;                      // [0, 98304)
            const float* src = (e < 49152) ? wih : whh;
            ushort* dst = (e < 49152) ? wih_b : whh_b;
            const int off = (e < 49152) ? e : e - 49152;
            const float4 f0 = ((const float4*)(src + off))[0];
            const float4 f1 = ((const float4*)(src + off))[1];
            us8 v;
            v[0] = f2bf(f0.x); v[1] = f2bf(f0.y); v[2] = f2bf(f0.z); v[3] = f2bf(f0.w);
            v[4] = f2bf(f1.x); v[5] = f2bf(f1.y); v[6] = f2bf(f1.z); v[7] = f2bf(f1.w);
            *(us8*)(dst + off) = v;
        }
        return;
    }

    __shared__ __align__(16) ushort A[64 * 128];
    const int rowbase = blockIdx.x * 64;
    {
#pragma unroll
        for (int i2 = 0; i2 < 2; ++i2) {
            const int i = tid + i2 * 512;
            const int r = i >> 4, kc = i & 15;
            const float4* s4 = (const float4*)(ne + (size_t)(rowbase + r) * NE);
            const float4 f0 = s4[kc * 2], f1 = s4[kc * 2 + 1];
            us8 v;
            v[0] = f2bf(f0.x); v[1] = f2bf(f0.y); v[2] = f2bf(f0.z); v[3] = f2bf(f0.w);
            v[4] = f2bf(f1.x); v[5] = f2bf(f1.y); v[6] = f2bf(f1.z); v[7] = f2bf(f1.w);
            *(us8*)&A[(r * 16 + (kc ^ (r & 7))) * 8] = v;
            *(us8*)&ne_b[(size_t)(rowbase + r) * NE + kc * 8] = v;
        }
    }
    __syncthreads();

    const int w = tid >> 6, l = tid & 63;
    const int lr = l & 15, lg = l >> 4;

    f32x4 acc[4][2] = {};
#pragma unroll
    for (int ks = 0; ks < 4; ++ks) {
        bf16x8 a[4], b[2];
#pragma unroll
        for (int mf = 0; mf < 4; ++mf) {
            const int r = mf * 16 + lr;
            a[mf] = *(const bf16x8*)&A[(r * 16 + ((ks * 4 + lg) ^ (r & 7))) * 8];
        }
#pragma unroll
        for (int nf = 0; nf < 2; ++nf) {
            const int j = w * 32 + nf * 16 + lr;
            const float* Wrow = (j < 128) ? (Wq + (size_t)j * 128 + ks * 32 + lg * 8)
                                          : (Wk + (size_t)(j - 128) * 128 + ks * 32 + lg * 8);
            const float4 wf0 = ((const float4*)Wrow)[0];
            const float4 wf1 = ((const float4*)Wrow)[1];
            union { us8 u; bf16x8 bv; } cv;
            cv.u[0] = f2bf(wf0.x); cv.u[1] = f2bf(wf0.y); cv.u[2] = f2bf(wf0.z); cv.u[3] = f2bf(wf0.w);
            cv.u[4] = f2bf(wf1.x); cv.u[5] = f2bf(wf1.y); cv.u[6] = f2bf(wf1.z); cv.u[7] = f2bf(wf1.w);
            b[nf] = cv.bv;
        }
#pragma unroll
        for (int mf = 0; mf < 4; ++mf)
#pragma unroll
            for (int nf = 0; nf < 2; ++nf)
                acc[mf][nf] = __builtin_amdgcn_mfma_f32_16x16x32_bf16(a[mf], b[nf], acc[mf][nf], 0, 0, 0);
    }
#pragma unroll
    for (int mf = 0; mf < 4; ++mf)
#pragma unroll
        for (int nf = 0; nf < 2; ++nf)
#pragma unroll
            for (int q = 0; q < 4; ++q) {
                const int row = rowbase + mf * 16 + lg * 4 + q;
                const int col = w * 32 + nf * 16 + lr;
                QKb[(size_t)row * 256 + col] = f2bf(acc[mf][nf][q]);
            }
}

// ---------------- Kernel C: fused edge-score + softmax + aggregate ----------
// 2 rows per wave. Bijective XCD map. urow loads deferred into the merge loop
// (issued as each d_p is broadcast) so they overlap the softmax shfl chain
// instead of holding 20 VGPRs across stages; __launch_bounds__(256,6) caps
// VGPR ~85 for 6 waves/SIMD occupancy (latency-bound regime).
__global__ __launch_bounds__(256, 6) void score_agg(
        const int2* __restrict__ edge_pack, const float* __restrict__ costs,
        const ushort* __restrict__ QKb, const ushort* __restrict__ ne_b,
        const float* __restrict__ m1w, const float* __restrict__ m1b,
        const float* __restrict__ m2w, const float* __restrict__ m2b,
        const float* __restrict__ nhw,
        unsigned* __restrict__ solu_b) {
    __shared__ float w1t[2][MSH][NH];
    __shared__ float b1t[MSH][NH];
    __shared__ float w2t[MSH][NH];
    __shared__ float b2s[NH];
    __shared__ float nws[NH];
    const int tid = threadIdx.x;
    {   // m1w layout [h][e][m] -> transposed [e][m][h]
        const int h = tid >> 5, e = (tid >> 4) & 1, m = tid & 15;
        w1t[e][m][h] = m1w[tid];
        if (tid < 128) {
            const int h2 = tid >> 4, m2 = tid & 15;
            b1t[m2][h2] = m1b[tid];
            w2t[m2][h2] = m2w[tid];
        }
        if (tid < NH) { b2s[tid] = m2b[tid]; nws[tid] = nhw[tid]; }
    }
    __syncthreads();

    // bijective XCD-aware remap: 4000 blocks, 8 rows/block (2 per wave)
    const int bid = blockIdx.x;
    const int xcd = bid & 7;
    const int idx = bid >> 3;              // [0,500)
    const int b = xcd + 8 * (idx / 125);   // 4 batch-groups per XCD
    const int gbase = (idx % 125) * 8 + ((tid >> 6) << 1);
    const int lane = tid & 63;
    const int h = lane & 7;
    const int sg = lane >> 3;

    // ---- stage 1: fused {dst, edge} gathers ----
    int dstp[2][2]; float edgep[2][2];
#pragma unroll
    for (int r = 0; r < 2; ++r) {
        const int2 e0 = edge_pack[(size_t)(sg * NB + b) * NG + (gbase + r)];
        dstp[r][0] = e0.x; edgep[r][0] = asf(e0.y);
        dstp[r][1] = 0; edgep[r][1] = 0.f;
        if (sg < 2) {
            const int2 e1 = edge_pack[(size_t)((8 + sg) * NB + b) * NG + (gbase + r)];
            dstp[r][1] = e1.x; edgep[r][1] = asf(e1.y);
        }
    }

    // ---- stage 2: K gathers (lane-local dst; pass-1 exec-masked) ----
    uint4 kk[2][2][2];
#pragma unroll
    for (int r = 0; r < 2; ++r) {
        {
            const uint4* Kr = (const uint4*)(QKb + (size_t)(b * NG + dstp[r][0]) * 256 + 128);
            kk[r][0][0] = Kr[h * 2]; kk[r][0][1] = Kr[h * 2 + 1];
        }
        kk[r][1][0] = make_uint4(0, 0, 0, 0);
        kk[r][1][1] = make_uint4(0, 0, 0, 0);
        if (sg < 2) {
            const uint4* Kr = (const uint4*)(QKb + (size_t)(b * NG + dstp[r][1]) * 256 + 128);
            kk[r][1][0] = Kr[h * 2]; kk[r][1][1] = Kr[h * 2 + 1];
        }
    }

    // ---- stage 3: Q rows (sequential) ----
    uint4 qq[2][2];
#pragma unroll
    for (int r = 0; r < 2; ++r) {
        const uint4* Qr = (const uint4*)(QKb + (size_t)(b * NG + gbase + r) * 256);
        qq[r][0] = Qr[h * 2]; qq[r][1] = Qr[h * 2 + 1];
    }

    // ---- stage 4: MLP + head reduce (4 independent chains) ----
    float val_p[2][2];
#pragma unroll
    for (int r = 0; r < 2; ++r)
#pragma unroll
        for (int p = 0; p < 2; ++p) {
            float dd = (dot8(qq[r][0], kk[r][p][0]) + dot8(qq[r][1], kk[r][p][1])) * 0.0625f;
            float ms2 = b2s[h];
#pragma unroll
            for (int m = 0; m < MSH; ++m) {
                float t = fmaf(dd, w1t[0][m][h], fmaf(edgep[r][p], w1t[1][m][h], b1t[m][h]));
                t = fmaxf(t, 0.f);
                ms2 = fmaf(t, w2t[m][h], ms2);
            }
            float contrib = ms2 * nws[h];
            contrib += __shfl_xor(contrib, 1);
            contrib += __shfl_xor(contrib, 2);
            contrib += __shfl_xor(contrib, 4);
            val_p[r][p] = contrib;
        }

    // ---- stages 5-7 per row: merge (+deferred urow loads), softmax, agg ----
    const float cinv = __builtin_amdgcn_rcpf(costs[((lane < NS) ? lane : 0) * NB + b]);
#pragma unroll
    for (int r = 0; r < 2; ++r) {
        const float va = __shfl(val_p[r][0], (lane & 7) * 8);
        const float vb = __shfl(val_p[r][1], (lane & 1) * 8);
        const int   da = __shfl(dstp[r][0], (lane & 7) * 8);
        const int   db = __shfl(dstp[r][1], (lane & 1) * 8);
        float v_own = ((lane < 8) ? va : vb) * cinv;
        const int d_own = (lane < 8) ? da : db;

        // merge: first-occurrence accumulates; issue urow load per broadcast d_p
        unsigned urow[NS];
        float acc = v_own;
        bool first = true;
#pragma unroll
        for (int p = 0; p < NS; ++p) {
            const int   d_p = __shfl(d_own, p);
            const float v_p = __shfl(v_own, p);
            urow[p] = ((const unsigned*)(ne_b + (size_t)(b * NG + d_p) * NE))[lane];
            const bool eq = (d_p == d_own);
            first = first && (!eq || p >= lane);
            acc += (eq && p > lane) ? v_p : 0.f;
        }
        const bool surv = (lane < NS) && first && (acc != 0.f);

        float mval = surv ? acc : -3.0e38f;
        mval = fmaxf(mval, __shfl_xor(mval, 1));
        mval = fmaxf(mval, __shfl_xor(mval, 2));
        mval = fmaxf(mval, __shfl_xor(mval, 4));
        mval = fmaxf(mval, __shfl_xor(mval, 8));
        const float e = surv ? __expf(acc - mval) : 0.f;
        float den = e;
        den += __shfl_xor(den, 1);
        den += __shfl_xor(den, 2);
        den += __shfl_xor(den, 4);
        den += __shfl_xor(den, 8);
        const float wt_own = e * __builtin_amdgcn_rcpf(den);

        const bool any = (__ballot(surv) != 0ull);

        float a0 = 0.f, a1 = 0.f;
        if (!any) {
            const unsigned* base = (const unsigned*)(ne_b + (size_t)b * NG * NE);
            for (int n = 0; n < NG; ++n) {
                const unsigned u = base[n * 64 + lane];
                a0 += bflo(u); a1 += bfhi(u);
            }
            const float invG = 1.f / NG;
            a0 *= invG; a1 *= invG;
        } else {
#pragma unroll
            for (int s = 0; s < NS; ++s) {
                const float wt = __shfl(wt_own, s);   // 0 for dropped entries
                a0 += wt * bflo(urow[s]);
                a1 += wt * bfhi(urow[s]);
            }
        }
        solu_b[(size_t)(b * NG + gbase + r) * 64 + lane] =
            (unsigned)f2bf(a0) | ((unsigned)f2bf(a1) << 16);
    }
}

// ---------------- Kernel D: fused GRU via MFMA (64-row tiles) ----------------
__global__ __launch_bounds__(512) void gru_mfma(
        const ushort* __restrict__ x_b,
        const float* __restrict__ h_in,
        const ushort* __restrict__ wih_b, const ushort* __restrict__ whh_b,
        const float* __restrict__ bih, const float* __restrict__ bhh,
        float* __restrict__ out0, float* __restrict__ out1) {
    __shared__ __align__(16) ushort X[64 * 128];
    __shared__ __align__(16) ushort H[64 * 128];
    const int tid = threadIdx.x;
    const int rowbase = blockIdx.x * 64;

    {
#pragma unroll
        for (int i2 = 0; i2 < 2; ++i2) {
            const int i = tid + i2 * 512;
            const int r = i >> 4, kc = i & 15;
            us8 xv = *(const us8*)&x_b[(size_t)(rowbase + r) * NE + kc * 8];
            *(us8*)&X[(r * 16 + (kc ^ (r & 7))) * 8] = xv;
            const float4* h4 = (const float4*)(h_in + (size_t)(rowbase + r) * NE);
            const float4 f0 = h4[kc * 2], f1 = h4[kc * 2 + 1];
            us8 hv;
            hv[0] = f2bf(f0.x); hv[1] = f2bf(f0.y); hv[2] = f2bf(f0.z); hv[3] = f2bf(f0.w);
            hv[4] = f2bf(f1.x); hv[5] = f2bf(f1.y); hv[6] = f2bf(f1.z); hv[7] = f2bf(f1.w);
            *(us8*)&H[(r * 16 + (kc ^ (r & 7))) * 8] = hv;
        }
    }
    __syncthreads();

    const int w = tid >> 6, l = tid & 63;
    const int lr = l & 15, lg = l >> 4;
    const int j = w * 16 + lr;

    f32x4 acc[4][6] = {};
#pragma unroll
    for (int ks = 0; ks < 4; ++ks) {
        bf16x8 bb[6];
#pragma unroll
        for (int g = 0; g < 3; ++g) {
            bb[g]     = *(const bf16x8*)&wih_b[(size_t)(g * 128 + j) * 128 + ks * 32 + lg * 8];
            bb[g + 3] = *(const bf16x8*)&whh_b[(size_t)(g * 128 + j) * 128 + ks * 32 + lg * 8];
        }
#pragma unroll
        for (int mf = 0; mf < 4; ++mf) {
            const int r = mf * 16 + lr;
            const int c = (r * 16 + ((ks * 4 + lg) ^ (r & 7))) * 8;
            const bf16x8 ax = *(const bf16x8*)&X[c];
            const bf16x8 ah = *(const bf16x8*)&H[c];
#pragma unroll
            for (int g = 0; g < 3; ++g) {
                acc[mf][g]     = __builtin_amdgcn_mfma_f32_16x16x32_bf16(ax, bb[g],     acc[mf][g],     0, 0, 0);
                acc[mf][g + 3] = __builtin_amdgcn_mfma_f32_16x16x32_bf16(ah, bb[g + 3], acc[mf][g + 3], 0, 0, 0);
            }
        }
    }

    const float bi0 = bih[j], bi1 = bih[128 + j], bi2 = bih[256 + j];
    const float bh0 = bhh[j], bh1 = bhh[128 + j], bh2 = bhh[256 + j];
#pragma unroll
    for (int mf = 0; mf < 4; ++mf) {
#pragma unroll
        for (int q = 0; q < 4; ++q) {
            const int row = rowbase + mf * 16 + lg * 4 + q;
            const float ir = acc[mf][0][q] + bi0;
            const float iz = acc[mf][1][q] + bi1;
            const float in_ = acc[mf][2][q] + bi2;
            const float hr = acc[mf][3][q] + bh0;
            const float hz = acc[mf][4][q] + bh1;
            const float hn = acc[mf][5][q] + bh2;
            const float rr = 1.f / (1.f + expf(-(ir + hr)));
            const float zz = 1.f / (1.f + expf(-(iz + hz)));
            const float nn = tanhf(in_ + rr * hn);
            const float hv = h_in[(size_t)row * NE + j];
            const float nv = (1.f - zz) * nn + zz * hv;
            const size_t o = (size_t)row * NE + j;
            out1[o] = nv;
            out0[o] = (nv > 0.f) ? nv : expm1f(nv);
        }
    }
}

extern "C" void kernel_launch(void* const* d_in, const int* in_sizes, int n_in,
                              void* d_out, int out_size, void* d_ws, size_t ws_size,
                              hipStream_t stream) {
    const float* ne    = (const float*)d_in[0];
    const int*   sol   = (const int*)d_in[1];
    const float* costs = (const float*)d_in[2];
    const float* dist  = (const float*)d_in[3];
    const float* old_h = (const float*)d_in[4];
    const float* Wq    = (const float*)d_in[5];
    const float* Wk    = (const float*)d_in[6];
    const float* m1w   = (const float*)d_in[7];
    const float* m1b   = (const float*)d_in[8];
    const float* m2w   = (const float*)d_in[9];
    const float* m2b   = (const float*)d_in[10];
    const float* nhw   = (const float*)d_in[11];
    const float* wih   = (const float*)d_in[12];
    const float* whh   = (const float*)d_in[13];
    const float* bih   = (const float*)d_in[14];
    const float* bhh   = (const float*)d_in[15];

    float* out0 = (float*)d_out;
    float* out1 = out0 + (size_t)NB * NG * NE;

    // workspace layout (16B aligned)
    ushort*   QKb       = (ushort*)d_ws;                               // 16.384 MB
    ushort*   ne_b      = QKb + (size_t)NB * NG * 256;                 // 8.192 MB
    int2*     edge_pack = (int2*)(ne_b + (size_t)NB * NG * NE);        // 2.56 MB
    unsigned* solu_b    = (unsigned*)(edge_pack + (size_t)NS * NB * NG);// 8.192 MB
    ushort*   wih_b     = (ushort*)(solu_b + (size_t)NB * NG * 64);    // 96 KB
    ushort*   whh_b     = wih_b + 384 * 128;                           // 96 KB

    qk_prep<<<500 + 625 + 24, 512, 0, stream>>>(
        ne, sol, dist, Wq, Wk, wih, whh,
        QKb, ne_b, edge_pack, wih_b, whh_b);
    score_agg<<<4000, 256, 0, stream>>>(
        edge_pack, costs, QKb, ne_b, m1w, m1b, m2w, m2b, nhw, solu_b);
    gru_mfma<<<(NB * NG) / 64, 512, 0, stream>>>(
        (const ushort*)solu_b, old_h, wih_b, whh_b, bih, bhh, out0, out1);
}

// Round 14
// 87.008 us; speedup vs baseline: 1.4024x; 1.4024x over previous
//
#include <hip/hip_runtime.h>
#include <math.h>

#define NS 10
#define NB 32
#define NG 1000
#define NE 128
#define NH 8
#define MSH 16

typedef __bf16 bf16x8 __attribute__((ext_vector_type(8)));
typedef float f32x4 __attribute__((ext_vector_type(4)));
typedef unsigned short ushort;
typedef ushort us8 __attribute__((ext_vector_type(8)));

__device__ __forceinline__ ushort f2bf(float f) {
    union { float f; unsigned u; } c; c.f = f;
    unsigned r = c.u + 0x7FFFu + ((c.u >> 16) & 1u);
    return (ushort)(r >> 16);
}
__device__ __forceinline__ float bflo(unsigned u) {
    union { unsigned v; float f; } c; c.v = u << 16; return c.f;
}
__device__ __forceinline__ float bfhi(unsigned u) {
    union { unsigned v; float f; } c; c.v = u & 0xFFFF0000u; return c.f;
}
__device__ __forceinline__ float asf(int i) {
    union { int i; float f; } c; c.i = i; return c.f;
}
__device__ __forceinline__ int asi(float f) {
    union { float f; int i; } c; c.f = f; return c.i;
}
__device__ __forceinline__ float dot8(uint4 q, uint4 k) {
    return bflo(q.x) * bflo(k.x) + bfhi(q.x) * bfhi(k.x)
         + bflo(q.y) * bflo(k.y) + bfhi(q.y) * bfhi(k.y)
         + bflo(q.z) * bflo(k.z) + bfhi(q.z) * bfhi(k.z)
         + bflo(q.w) * bflo(k.w) + bfhi(q.w) * bfhi(k.w);
}

// ---------------- Kernel A: QK GEMM (blocks<500, 64-row tiles) + scatter + wcvt
// QKb rows: 256 bf16 (Q cols 0-127, K cols 128-255). edge_pack[sb][src] =
// {dst, dist_bits}. B-frags read Wq/Wk f32 directly, convert in-register.
__global__ __launch_bounds__(512) void qk_prep(
        const float* __restrict__ ne,
        const int* __restrict__ sol, const float* __restrict__ dist,
        const float* __restrict__ Wq, const float* __restrict__ Wk,
        const float* __restrict__ wih, const float* __restrict__ whh,
        ushort* __restrict__ QKb, ushort* __restrict__ ne_b,
        int2* __restrict__ edge_pack,
        ushort* __restrict__ wih_b, ushort* __restrict__ whh_b) {
    const int tid = threadIdx.x;
    if (blockIdx.x >= 500) {
        const int bid2 = blockIdx.x - 500;
        if (bid2 < 625) {
            // edge_pack scatter: 625*512 = 320000 edges
            const int gidx = bid2 * 512 + tid;         // (s*NB+b)*NG + t
            const int sb = gidx / NG;
            const int t = gidx - sb * NG;
            const int* srow = sol + (size_t)sb * NG;
            const int src = srow[t];
            const int tn = (t + 1 == NG) ? 0 : t + 1;
            const int dst = srow[tn];
            const int b = sb & 31;                     // NB = 32
            const float ev = dist[(size_t)(b * NG + src) * NG + dst];
            edge_pack[(size_t)sb * NG + src] = make_int2(dst, asi(ev));
        } else {
            const int wt = (bid2 - 625) * 512 + tid;   // 12288 chunk threads
            const int e = wt * 8;                      // [0, 98304)
            const float* src = (e < 49152) ? wih : whh;
            ushort* dst = (e < 49152) ? wih_b : whh_b;
            const int off = (e < 49152) ? e : e - 49152;
            const float4 f0 = ((const float4*)(src + off))[0];
            const float4 f1 = ((const float4*)(src + off))[1];
            us8 v;
            v[0] = f2bf(f0.x); v[1] = f2bf(f0.y); v[2] = f2bf(f0.z); v[3] = f2bf(f0.w);
            v[4] = f2bf(f1.x); v[5] = f2bf(f1.y); v[6] = f2bf(f1.z); v[7] = f2bf(f1.w);
            *(us8*)(dst + off) = v;
        }
        return;
    }

    __shared__ __align__(16) ushort A[64 * 128];
    const int rowbase = blockIdx.x * 64;
    {
#pragma unroll
        for (int i2 = 0; i2 < 2; ++i2) {
            const int i = tid + i2 * 512;
            const int r = i >> 4, kc = i & 15;
            const float4* s4 = (const float4*)(ne + (size_t)(rowbase + r) * NE);
            const float4 f0 = s4[kc * 2], f1 = s4[kc * 2 + 1];
            us8 v;
            v[0] = f2bf(f0.x); v[1] = f2bf(f0.y); v[2] = f2bf(f0.z); v[3] = f2bf(f0.w);
            v[4] = f2bf(f1.x); v[5] = f2bf(f1.y); v[6] = f2bf(f1.z); v[7] = f2bf(f1.w);
            *(us8*)&A[(r * 16 + (kc ^ (r & 7))) * 8] = v;
            *(us8*)&ne_b[(size_t)(rowbase + r) * NE + kc * 8] = v;
        }
    }
    __syncthreads();

    const int w = tid >> 6, l = tid & 63;
    const int lr = l & 15, lg = l >> 4;

    f32x4 acc[4][2] = {};
#pragma unroll
    for (int ks = 0; ks < 4; ++ks) {
        bf16x8 a[4], b[2];
#pragma unroll
        for (int mf = 0; mf < 4; ++mf) {
            const int r = mf * 16 + lr;
            a[mf] = *(const bf16x8*)&A[(r * 16 + ((ks * 4 + lg) ^ (r & 7))) * 8];
        }
#pragma unroll
        for (int nf = 0; nf < 2; ++nf) {
            const int j = w * 32 + nf * 16 + lr;
            const float* Wrow = (j < 128) ? (Wq + (size_t)j * 128 + ks * 32 + lg * 8)
                                          : (Wk + (size_t)(j - 128) * 128 + ks * 32 + lg * 8);
            const float4 wf0 = ((const float4*)Wrow)[0];
            const float4 wf1 = ((const float4*)Wrow)[1];
            union { us8 u; bf16x8 bv; } cv;
            cv.u[0] = f2bf(wf0.x); cv.u[1] = f2bf(wf0.y); cv.u[2] = f2bf(wf0.z); cv.u[3] = f2bf(wf0.w);
            cv.u[4] = f2bf(wf1.x); cv.u[5] = f2bf(wf1.y); cv.u[6] = f2bf(wf1.z); cv.u[7] = f2bf(wf1.w);
            b[nf] = cv.bv;
        }
#pragma unroll
        for (int mf = 0; mf < 4; ++mf)
#pragma unroll
            for (int nf = 0; nf < 2; ++nf)
                acc[mf][nf] = __builtin_amdgcn_mfma_f32_16x16x32_bf16(a[mf], b[nf], acc[mf][nf], 0, 0, 0);
    }
#pragma unroll
    for (int mf = 0; mf < 4; ++mf)
#pragma unroll
        for (int nf = 0; nf < 2; ++nf)
#pragma unroll
            for (int q = 0; q < 4; ++q) {
                const int row = rowbase + mf * 16 + lg * 4 + q;
                const int col = w * 32 + nf * 16 + lr;
                QKb[(size_t)row * 256 + col] = f2bf(acc[mf][nf][q]);
            }
}

// ---------------- Kernel C: fused edge-score + softmax + aggregate ----------
// 2 rows per wave. Bijective XCD map. urow loads deferred into the merge loop
// (reduces peak live VGPRs by ~20); NO min-waves bound — R13's (256,6) forced
// VGPR=40 and 152MB of scratch spills. Let the allocator pick.
__global__ __launch_bounds__(256) void score_agg(
        const int2* __restrict__ edge_pack, const float* __restrict__ costs,
        const ushort* __restrict__ QKb, const ushort* __restrict__ ne_b,
        const float* __restrict__ m1w, const float* __restrict__ m1b,
        const float* __restrict__ m2w, const float* __restrict__ m2b,
        const float* __restrict__ nhw,
        unsigned* __restrict__ solu_b) {
    __shared__ float w1t[2][MSH][NH];
    __shared__ float b1t[MSH][NH];
    __shared__ float w2t[MSH][NH];
    __shared__ float b2s[NH];
    __shared__ float nws[NH];
    const int tid = threadIdx.x;
    {   // m1w layout [h][e][m] -> transposed [e][m][h]
        const int h = tid >> 5, e = (tid >> 4) & 1, m = tid & 15;
        w1t[e][m][h] = m1w[tid];
        if (tid < 128) {
            const int h2 = tid >> 4, m2 = tid & 15;
            b1t[m2][h2] = m1b[tid];
            w2t[m2][h2] = m2w[tid];
        }
        if (tid < NH) { b2s[tid] = m2b[tid]; nws[tid] = nhw[tid]; }
    }
    __syncthreads();

    // bijective XCD-aware remap: 4000 blocks, 8 rows/block (2 per wave)
    const int bid = blockIdx.x;
    const int xcd = bid & 7;
    const int idx = bid >> 3;              // [0,500)
    const int b = xcd + 8 * (idx / 125);   // 4 batch-groups per XCD
    const int gbase = (idx % 125) * 8 + ((tid >> 6) << 1);
    const int lane = tid & 63;
    const int h = lane & 7;
    const int sg = lane >> 3;

    // ---- stage 1: fused {dst, edge} gathers ----
    int dstp[2][2]; float edgep[2][2];
#pragma unroll
    for (int r = 0; r < 2; ++r) {
        const int2 e0 = edge_pack[(size_t)(sg * NB + b) * NG + (gbase + r)];
        dstp[r][0] = e0.x; edgep[r][0] = asf(e0.y);
        dstp[r][1] = 0; edgep[r][1] = 0.f;
        if (sg < 2) {
            const int2 e1 = edge_pack[(size_t)((8 + sg) * NB + b) * NG + (gbase + r)];
            dstp[r][1] = e1.x; edgep[r][1] = asf(e1.y);
        }
    }

    // ---- stage 2: K gathers (lane-local dst; pass-1 exec-masked) ----
    uint4 kk[2][2][2];
#pragma unroll
    for (int r = 0; r < 2; ++r) {
        {
            const uint4* Kr = (const uint4*)(QKb + (size_t)(b * NG + dstp[r][0]) * 256 + 128);
            kk[r][0][0] = Kr[h * 2]; kk[r][0][1] = Kr[h * 2 + 1];
        }
        kk[r][1][0] = make_uint4(0, 0, 0, 0);
        kk[r][1][1] = make_uint4(0, 0, 0, 0);
        if (sg < 2) {
            const uint4* Kr = (const uint4*)(QKb + (size_t)(b * NG + dstp[r][1]) * 256 + 128);
            kk[r][1][0] = Kr[h * 2]; kk[r][1][1] = Kr[h * 2 + 1];
        }
    }

    // ---- stage 3: Q rows (sequential) ----
    uint4 qq[2][2];
#pragma unroll
    for (int r = 0; r < 2; ++r) {
        const uint4* Qr = (const uint4*)(QKb + (size_t)(b * NG + gbase + r) * 256);
        qq[r][0] = Qr[h * 2]; qq[r][1] = Qr[h * 2 + 1];
    }

    // ---- stage 4: MLP + head reduce (4 independent chains) ----
    float val_p[2][2];
#pragma unroll
    for (int r = 0; r < 2; ++r)
#pragma unroll
        for (int p = 0; p < 2; ++p) {
            float dd = (dot8(qq[r][0], kk[r][p][0]) + dot8(qq[r][1], kk[r][p][1])) * 0.0625f;
            float ms2 = b2s[h];
#pragma unroll
            for (int m = 0; m < MSH; ++m) {
                float t = fmaf(dd, w1t[0][m][h], fmaf(edgep[r][p], w1t[1][m][h], b1t[m][h]));
                t = fmaxf(t, 0.f);
                ms2 = fmaf(t, w2t[m][h], ms2);
            }
            float contrib = ms2 * nws[h];
            contrib += __shfl_xor(contrib, 1);
            contrib += __shfl_xor(contrib, 2);
            contrib += __shfl_xor(contrib, 4);
            val_p[r][p] = contrib;
        }

    // ---- stages 5-7 per row: merge (+deferred urow loads), softmax, agg ----
    const float cinv = __builtin_amdgcn_rcpf(costs[((lane < NS) ? lane : 0) * NB + b]);
#pragma unroll
    for (int r = 0; r < 2; ++r) {
        const float va = __shfl(val_p[r][0], (lane & 7) * 8);
        const float vb = __shfl(val_p[r][1], (lane & 1) * 8);
        const int   da = __shfl(dstp[r][0], (lane & 7) * 8);
        const int   db = __shfl(dstp[r][1], (lane & 1) * 8);
        float v_own = ((lane < 8) ? va : vb) * cinv;
        const int d_own = (lane < 8) ? da : db;

        // merge: first-occurrence accumulates; issue urow load per broadcast d_p
        unsigned urow[NS];
        float acc = v_own;
        bool first = true;
#pragma unroll
        for (int p = 0; p < NS; ++p) {
            const int   d_p = __shfl(d_own, p);
            const float v_p = __shfl(v_own, p);
            urow[p] = ((const unsigned*)(ne_b + (size_t)(b * NG + d_p) * NE))[lane];
            const bool eq = (d_p == d_own);
            first = first && (!eq || p >= lane);
            acc += (eq && p > lane) ? v_p : 0.f;
        }
        const bool surv = (lane < NS) && first && (acc != 0.f);

        float mval = surv ? acc : -3.0e38f;
        mval = fmaxf(mval, __shfl_xor(mval, 1));
        mval = fmaxf(mval, __shfl_xor(mval, 2));
        mval = fmaxf(mval, __shfl_xor(mval, 4));
        mval = fmaxf(mval, __shfl_xor(mval, 8));
        const float e = surv ? __expf(acc - mval) : 0.f;
        float den = e;
        den += __shfl_xor(den, 1);
        den += __shfl_xor(den, 2);
        den += __shfl_xor(den, 4);
        den += __shfl_xor(den, 8);
        const float wt_own = e * __builtin_amdgcn_rcpf(den);

        const bool any = (__ballot(surv) != 0ull);

        float a0 = 0.f, a1 = 0.f;
        if (!any) {
            const unsigned* base = (const unsigned*)(ne_b + (size_t)b * NG * NE);
            for (int n = 0; n < NG; ++n) {
                const unsigned u = base[n * 64 + lane];
                a0 += bflo(u); a1 += bfhi(u);
            }
            const float invG = 1.f / NG;
            a0 *= invG; a1 *= invG;
        } else {
#pragma unroll
            for (int s = 0; s < NS; ++s) {
                const float wt = __shfl(wt_own, s);   // 0 for dropped entries
                a0 += wt * bflo(urow[s]);
                a1 += wt * bfhi(urow[s]);
            }
        }
        solu_b[(size_t)(b * NG + gbase + r) * 64 + lane] =
            (unsigned)f2bf(a0) | ((unsigned)f2bf(a1) << 16);
    }
}

// ---------------- Kernel D: fused GRU via MFMA (64-row tiles) ----------------
__global__ __launch_bounds__(512) void gru_mfma(
        const ushort* __restrict__ x_b,
        const float* __restrict__ h_in,
        const ushort* __restrict__ wih_b, const ushort* __restrict__ whh_b,
        const float* __restrict__ bih, const float* __restrict__ bhh,
        float* __restrict__ out0, float* __restrict__ out1) {
    __shared__ __align__(16) ushort X[64 * 128];
    __shared__ __align__(16) ushort H[64 * 128];
    const int tid = threadIdx.x;
    const int rowbase = blockIdx.x * 64;

    {
#pragma unroll
        for (int i2 = 0; i2 < 2; ++i2) {
            const int i = tid + i2 * 512;
            const int r = i >> 4, kc = i & 15;
            us8 xv = *(const us8*)&x_b[(size_t)(rowbase + r) * NE + kc * 8];
            *(us8*)&X[(r * 16 + (kc ^ (r & 7))) * 8] = xv;
            const float4* h4 = (const float4*)(h_in + (size_t)(rowbase + r) * NE);
            const float4 f0 = h4[kc * 2], f1 = h4[kc * 2 + 1];
            us8 hv;
            hv[0] = f2bf(f0.x); hv[1] = f2bf(f0.y); hv[2] = f2bf(f0.z); hv[3] = f2bf(f0.w);
            hv[4] = f2bf(f1.x); hv[5] = f2bf(f1.y); hv[6] = f2bf(f1.z); hv[7] = f2bf(f1.w);
            *(us8*)&H[(r * 16 + (kc ^ (r & 7))) * 8] = hv;
        }
    }
    __syncthreads();

    const int w = tid >> 6, l = tid & 63;
    const int lr = l & 15, lg = l >> 4;
    const int j = w * 16 + lr;

    f32x4 acc[4][6] = {};
#pragma unroll
    for (int ks = 0; ks < 4; ++ks) {
        bf16x8 bb[6];
#pragma unroll
        for (int g = 0; g < 3; ++g) {
            bb[g]     = *(const bf16x8*)&wih_b[(size_t)(g * 128 + j) * 128 + ks * 32 + lg * 8];
            bb[g + 3] = *(const bf16x8*)&whh_b[(size_t)(g * 128 + j) * 128 + ks * 32 + lg * 8];
        }
#pragma unroll
        for (int mf = 0; mf < 4; ++mf) {
            const int r = mf * 16 + lr;
            const int c = (r * 16 + ((ks * 4 + lg) ^ (r & 7))) * 8;
            const bf16x8 ax = *(const bf16x8*)&X[c];
            const bf16x8 ah = *(const bf16x8*)&H[c];
#pragma unroll
            for (int g = 0; g < 3; ++g) {
                acc[mf][g]     = __builtin_amdgcn_mfma_f32_16x16x32_bf16(ax, bb[g],     acc[mf][g],     0, 0, 0);
                acc[mf][g + 3] = __builtin_amdgcn_mfma_f32_16x16x32_bf16(ah, bb[g + 3], acc[mf][g + 3], 0, 0, 0);
            }
        }
    }

    const float bi0 = bih[j], bi1 = bih[128 + j], bi2 = bih[256 + j];
    const float bh0 = bhh[j], bh1 = bhh[128 + j], bh2 = bhh[256 + j];
#pragma unroll
    for (int mf = 0; mf < 4; ++mf) {
#pragma unroll
        for (int q = 0; q < 4; ++q) {
            const int row = rowbase + mf * 16 + lg * 4 + q;
            const float ir = acc[mf][0][q] + bi0;
            const float iz = acc[mf][1][q] + bi1;
            const float in_ = acc[mf][2][q] + bi2;
            const float hr = acc[mf][3][q] + bh0;
            const float hz = acc[mf][4][q] + bh1;
            const float hn = acc[mf][5][q] + bh2;
            const float rr = 1.f / (1.f + expf(-(ir + hr)));
            const float zz = 1.f / (1.f + expf(-(iz + hz)));
            const float nn = tanhf(in_ + rr * hn);
            const float hv = h_in[(size_t)row * NE + j];
            const float nv = (1.f - zz) * nn + zz * hv;
            const size_t o = (size_t)row * NE + j;
            out1[o] = nv;
            out0[o] = (nv > 0.f) ? nv : expm1f(nv);
        }
    }
}

extern "C" void kernel_launch(void* const* d_in, const int* in_sizes, int n_in,
                              void* d_out, int out_size, void* d_ws, size_t ws_size,
                              hipStream_t stream) {
    const float* ne    = (const float*)d_in[0];
    const int*   sol   = (const int*)d_in[1];
    const float* costs = (const float*)d_in[2];
    const float* dist  = (const float*)d_in[3];
    const float* old_h = (const float*)d_in[4];
    const float* Wq    = (const float*)d_in[5];
    const float* Wk    = (const float*)d_in[6];
    const float* m1w   = (const float*)d_in[7];
    const float* m1b   = (const float*)d_in[8];
    const float* m2w   = (const float*)d_in[9];
    const float* m2b   = (const float*)d_in[10];
    const float* nhw   = (const float*)d_in[11];
    const float* wih   = (const float*)d_in[12];
    const float* whh   = (const float*)d_in[13];
    const float* bih   = (const float*)d_in[14];
    const float* bhh   = (const float*)d_in[15];

    float* out0 = (float*)d_out;
    float* out1 = out0 + (size_t)NB * NG * NE;

    // workspace layout (16B aligned)
    ushort*   QKb       = (ushort*)d_ws;                               // 16.384 MB
    ushort*   ne_b      = QKb + (size_t)NB * NG * 256;                 // 8.192 MB
    int2*     edge_pack = (int2*)(ne_b + (size_t)NB * NG * NE);        // 2.56 MB
    unsigned* solu_b    = (unsigned*)(edge_pack + (size_t)NS * NB * NG);// 8.192 MB
    ushort*   wih_b     = (ushort*)(solu_b + (size_t)NB * NG * 64);    // 96 KB
    ushort*   whh_b     = wih_b + 384 * 128;                           // 96 KB

    qk_prep<<<500 + 625 + 24, 512, 0, stream>>>(
        ne, sol, dist, Wq, Wk, wih, whh,
        QKb, ne_b, edge_pack, wih_b, whh_b);
    score_agg<<<4000, 256, 0, stream>>>(
        edge_pack, costs, QKb, ne_b, m1w, m1b, m2w, m2b, nhw, solu_b);
    gru_mfma<<<(NB * NG) / 64, 512, 0, stream>>>(
        (const ushort*)solu_b, old_h, wih_b, whh_b, bih, bhh, out0, out1);
}

// Round 15
// 85.804 us; speedup vs baseline: 1.4221x; 1.0140x over previous
//
#include <hip/hip_runtime.h>
#include <math.h>

#define NS 10
#define NB 32
#define NG 1000
#define NE 128
#define NH 8
#define MSH 16

typedef __bf16 bf16x8 __attribute__((ext_vector_type(8)));
typedef float f32x4 __attribute__((ext_vector_type(4)));
typedef unsigned short ushort;
typedef ushort us8 __attribute__((ext_vector_type(8)));

__device__ __forceinline__ ushort f2bf(float f) {
    union { float f; unsigned u; } c; c.f = f;
    unsigned r = c.u + 0x7FFFu + ((c.u >> 16) & 1u);
    return (ushort)(r >> 16);
}
__device__ __forceinline__ float bflo(unsigned u) {
    union { unsigned v; float f; } c; c.v = u << 16; return c.f;
}
__device__ __forceinline__ float bfhi(unsigned u) {
    union { unsigned v; float f; } c; c.v = u & 0xFFFF0000u; return c.f;
}
__device__ __forceinline__ float asf(int i) {
    union { int i; float f; } c; c.i = i; return c.f;
}
__device__ __forceinline__ int asi(float f) {
    union { float f; int i; } c; c.f = f; return c.i;
}
__device__ __forceinline__ float dot8(uint4 q, uint4 k) {
    return bflo(q.x) * bflo(k.x) + bfhi(q.x) * bfhi(k.x)
         + bflo(q.y) * bflo(k.y) + bfhi(q.y) * bfhi(k.y)
         + bflo(q.z) * bflo(k.z) + bfhi(q.z) * bfhi(k.z)
         + bflo(q.w) * bflo(k.w) + bfhi(q.w) * bfhi(k.w);
}

// ---------------- Kernel A: QK GEMM (blocks<250, 128-row tiles) + scatter + wcvt
// QKb rows: 256 bf16 (Q cols 0-127, K cols 128-255). edge_pack[sb][src] =
// {dst, dist_bits}. B-frags read Wq/Wk f32 directly, convert in-register;
// 128-row tile halves that redundancy vs R12's 64-row.
__global__ __launch_bounds__(512) void qk_prep(
        const float* __restrict__ ne,
        const int* __restrict__ sol, const float* __restrict__ dist,
        const float* __restrict__ Wq, const float* __restrict__ Wk,
        const float* __restrict__ wih, const float* __restrict__ whh,
        ushort* __restrict__ QKb, ushort* __restrict__ ne_b,
        int2* __restrict__ edge_pack,
        ushort* __restrict__ wih_b, ushort* __restrict__ whh_b) {
    const int tid = threadIdx.x;
    if (blockIdx.x >= 250) {
        const int bid2 = blockIdx.x - 250;
        if (bid2 < 625) {
            // edge_pack scatter: 625*512 = 320000 edges
            const int gidx = bid2 * 512 + tid;         // (s*NB+b)*NG + t
            const int sb = gidx / NG;
            const int t = gidx - sb * NG;
            const int* srow = sol + (size_t)sb * NG;
            const int src = srow[t];
            const int tn = (t + 1 == NG) ? 0 : t + 1;
            const int dst = srow[tn];
            const int b = sb & 31;                     // NB = 32
            const float ev = dist[(size_t)(b * NG + src) * NG + dst];
            edge_pack[(size_t)sb * NG + src] = make_int2(dst, asi(ev));
        } else {
            const int wt = (bid2 - 625) * 512 + tid;   // 12288 chunk threads
            const int e = wt * 8;                      // [0, 98304)
            const float* src = (e < 49152) ? wih : whh;
            ushort* dst = (e < 49152) ? wih_b : whh_b;
            const int off = (e < 49152) ? e : e - 49152;
            const float4 f0 = ((const float4*)(src + off))[0];
            const float4 f1 = ((const float4*)(src + off))[1];
            us8 v;
            v[0] = f2bf(f0.x); v[1] = f2bf(f0.y); v[2] = f2bf(f0.z); v[3] = f2bf(f0.w);
            v[4] = f2bf(f1.x); v[5] = f2bf(f1.y); v[6] = f2bf(f1.z); v[7] = f2bf(f1.w);
            *(us8*)(dst + off) = v;
        }
        return;
    }

    __shared__ __align__(16) ushort A[128 * 128];   // 32 KB
    const int rowbase = blockIdx.x * 128;
    {
#pragma unroll
        for (int i2 = 0; i2 < 4; ++i2) {
            const int i = tid + i2 * 512;
            const int r = i >> 4, kc = i & 15;
            const float4* s4 = (const float4*)(ne + (size_t)(rowbase + r) * NE);
            const float4 f0 = s4[kc * 2], f1 = s4[kc * 2 + 1];
            us8 v;
            v[0] = f2bf(f0.x); v[1] = f2bf(f0.y); v[2] = f2bf(f0.z); v[3] = f2bf(f0.w);
            v[4] = f2bf(f1.x); v[5] = f2bf(f1.y); v[6] = f2bf(f1.z); v[7] = f2bf(f1.w);
            *(us8*)&A[(r * 16 + (kc ^ (r & 7))) * 8] = v;
            *(us8*)&ne_b[(size_t)(rowbase + r) * NE + kc * 8] = v;
        }
    }
    __syncthreads();

    const int w = tid >> 6, l = tid & 63;
    const int lr = l & 15, lg = l >> 4;

    f32x4 acc[8][2] = {};
#pragma unroll
    for (int ks = 0; ks < 4; ++ks) {
        bf16x8 a[8], b[2];
#pragma unroll
        for (int mf = 0; mf < 8; ++mf) {
            const int r = mf * 16 + lr;
            a[mf] = *(const bf16x8*)&A[(r * 16 + ((ks * 4 + lg) ^ (r & 7))) * 8];
        }
#pragma unroll
        for (int nf = 0; nf < 2; ++nf) {
            const int j = w * 32 + nf * 16 + lr;
            const float* Wrow = (j < 128) ? (Wq + (size_t)j * 128 + ks * 32 + lg * 8)
                                          : (Wk + (size_t)(j - 128) * 128 + ks * 32 + lg * 8);
            const float4 wf0 = ((const float4*)Wrow)[0];
            const float4 wf1 = ((const float4*)Wrow)[1];
            union { us8 u; bf16x8 bv; } cv;
            cv.u[0] = f2bf(wf0.x); cv.u[1] = f2bf(wf0.y); cv.u[2] = f2bf(wf0.z); cv.u[3] = f2bf(wf0.w);
            cv.u[4] = f2bf(wf1.x); cv.u[5] = f2bf(wf1.y); cv.u[6] = f2bf(wf1.z); cv.u[7] = f2bf(wf1.w);
            b[nf] = cv.bv;
        }
#pragma unroll
        for (int mf = 0; mf < 8; ++mf)
#pragma unroll
            for (int nf = 0; nf < 2; ++nf)
                acc[mf][nf] = __builtin_amdgcn_mfma_f32_16x16x32_bf16(a[mf], b[nf], acc[mf][nf], 0, 0, 0);
    }
#pragma unroll
    for (int mf = 0; mf < 8; ++mf)
#pragma unroll
        for (int nf = 0; nf < 2; ++nf)
#pragma unroll
            for (int q = 0; q < 4; ++q) {
                const int row = rowbase + mf * 16 + lg * 4 + q;
                const int col = w * 32 + nf * 16 + lr;
                QKb[(size_t)row * 256 + col] = f2bf(acc[mf][nf][q]);
            }
}

// ---------------- Kernel C: fused edge-score + softmax + aggregate ----------
// 2 rows per wave. Bijective XCD map. Q loads hoisted first (no deps -> in
// flight under the edge_pack chain); urow loads deferred into the merge loop;
// no min-waves bound (R13 lesson: forced bounds -> spills).
__global__ __launch_bounds__(256) void score_agg(
        const int2* __restrict__ edge_pack, const float* __restrict__ costs,
        const ushort* __restrict__ QKb, const ushort* __restrict__ ne_b,
        const float* __restrict__ m1w, const float* __restrict__ m1b,
        const float* __restrict__ m2w, const float* __restrict__ m2b,
        const float* __restrict__ nhw,
        unsigned* __restrict__ solu_b) {
    __shared__ float w1t[2][MSH][NH];
    __shared__ float b1t[MSH][NH];
    __shared__ float w2t[MSH][NH];
    __shared__ float b2s[NH];
    __shared__ float nws[NH];
    const int tid = threadIdx.x;
    {   // m1w layout [h][e][m] -> transposed [e][m][h]
        const int h = tid >> 5, e = (tid >> 4) & 1, m = tid & 15;
        w1t[e][m][h] = m1w[tid];
        if (tid < 128) {
            const int h2 = tid >> 4, m2 = tid & 15;
            b1t[m2][h2] = m1b[tid];
            w2t[m2][h2] = m2w[tid];
        }
        if (tid < NH) { b2s[tid] = m2b[tid]; nws[tid] = nhw[tid]; }
    }
    __syncthreads();

    // bijective XCD-aware remap: 4000 blocks, 8 rows/block (2 per wave)
    const int bid = blockIdx.x;
    const int xcd = bid & 7;
    const int idx = bid >> 3;              // [0,500)
    const int b = xcd + 8 * (idx / 125);   // 4 batch-groups per XCD
    const int gbase = (idx % 125) * 8 + ((tid >> 6) << 1);
    const int lane = tid & 63;
    const int h = lane & 7;
    const int sg = lane >> 3;

    // ---- stage 0: Q rows (sequential, dependency-free -> issue first) ----
    uint4 qq[2][2];
#pragma unroll
    for (int r = 0; r < 2; ++r) {
        const uint4* Qr = (const uint4*)(QKb + (size_t)(b * NG + gbase + r) * 256);
        qq[r][0] = Qr[h * 2]; qq[r][1] = Qr[h * 2 + 1];
    }

    // ---- stage 1: fused {dst, edge} gathers ----
    int dstp[2][2]; float edgep[2][2];
#pragma unroll
    for (int r = 0; r < 2; ++r) {
        const int2 e0 = edge_pack[(size_t)(sg * NB + b) * NG + (gbase + r)];
        dstp[r][0] = e0.x; edgep[r][0] = asf(e0.y);
        dstp[r][1] = 0; edgep[r][1] = 0.f;
        if (sg < 2) {
            const int2 e1 = edge_pack[(size_t)((8 + sg) * NB + b) * NG + (gbase + r)];
            dstp[r][1] = e1.x; edgep[r][1] = asf(e1.y);
        }
    }

    // ---- stage 2: K gathers (lane-local dst; pass-1 exec-masked) ----
    uint4 kk[2][2][2];
#pragma unroll
    for (int r = 0; r < 2; ++r) {
        {
            const uint4* Kr = (const uint4*)(QKb + (size_t)(b * NG + dstp[r][0]) * 256 + 128);
            kk[r][0][0] = Kr[h * 2]; kk[r][0][1] = Kr[h * 2 + 1];
        }
        kk[r][1][0] = make_uint4(0, 0, 0, 0);
        kk[r][1][1] = make_uint4(0, 0, 0, 0);
        if (sg < 2) {
            const uint4* Kr = (const uint4*)(QKb + (size_t)(b * NG + dstp[r][1]) * 256 + 128);
            kk[r][1][0] = Kr[h * 2]; kk[r][1][1] = Kr[h * 2 + 1];
        }
    }

    // ---- stage 3: MLP + head reduce (4 independent chains) ----
    float val_p[2][2];
#pragma unroll
    for (int r = 0; r < 2; ++r)
#pragma unroll
        for (int p = 0; p < 2; ++p) {
            float dd = (dot8(qq[r][0], kk[r][p][0]) + dot8(qq[r][1], kk[r][p][1])) * 0.0625f;
            float ms2 = b2s[h];
#pragma unroll
            for (int m = 0; m < MSH; ++m) {
                float t = fmaf(dd, w1t[0][m][h], fmaf(edgep[r][p], w1t[1][m][h], b1t[m][h]));
                t = fmaxf(t, 0.f);
                ms2 = fmaf(t, w2t[m][h], ms2);
            }
            float contrib = ms2 * nws[h];
            contrib += __shfl_xor(contrib, 1);
            contrib += __shfl_xor(contrib, 2);
            contrib += __shfl_xor(contrib, 4);
            val_p[r][p] = contrib;
        }

    // ---- stages 4-6 per row: merge (+deferred urow loads), softmax, agg ----
    const float cinv = __builtin_amdgcn_rcpf(costs[((lane < NS) ? lane : 0) * NB + b]);
#pragma unroll
    for (int r = 0; r < 2; ++r) {
        const float va = __shfl(val_p[r][0], (lane & 7) * 8);
        const float vb = __shfl(val_p[r][1], (lane & 1) * 8);
        const int   da = __shfl(dstp[r][0], (lane & 7) * 8);
        const int   db = __shfl(dstp[r][1], (lane & 1) * 8);
        float v_own = ((lane < 8) ? va : vb) * cinv;
        const int d_own = (lane < 8) ? da : db;

        // merge: first-occurrence accumulates; issue urow load per broadcast d_p
        unsigned urow[NS];
        float acc = v_own;
        bool first = true;
#pragma unroll
        for (int p = 0; p < NS; ++p) {
            const int   d_p = __shfl(d_own, p);
            const float v_p = __shfl(v_own, p);
            urow[p] = ((const unsigned*)(ne_b + (size_t)(b * NG + d_p) * NE))[lane];
            const bool eq = (d_p == d_own);
            first = first && (!eq || p >= lane);
            acc += (eq && p > lane) ? v_p : 0.f;
        }
        const bool surv = (lane < NS) && first && (acc != 0.f);

        float mval = surv ? acc : -3.0e38f;
        mval = fmaxf(mval, __shfl_xor(mval, 1));
        mval = fmaxf(mval, __shfl_xor(mval, 2));
        mval = fmaxf(mval, __shfl_xor(mval, 4));
        mval = fmaxf(mval, __shfl_xor(mval, 8));
        const float e = surv ? __expf(acc - mval) : 0.f;
        float den = e;
        den += __shfl_xor(den, 1);
        den += __shfl_xor(den, 2);
        den += __shfl_xor(den, 4);
        den += __shfl_xor(den, 8);
        const float wt_own = e * __builtin_amdgcn_rcpf(den);

        const bool any = (__ballot(surv) != 0ull);

        float a0 = 0.f, a1 = 0.f;
        if (!any) {
            const unsigned* base = (const unsigned*)(ne_b + (size_t)b * NG * NE);
            for (int n = 0; n < NG; ++n) {
                const unsigned u = base[n * 64 + lane];
                a0 += bflo(u); a1 += bfhi(u);
            }
            const float invG = 1.f / NG;
            a0 *= invG; a1 *= invG;
        } else {
#pragma unroll
            for (int s = 0; s < NS; ++s) {
                const float wt = __shfl(wt_own, s);   // 0 for dropped entries
                a0 += wt * bflo(urow[s]);
                a1 += wt * bfhi(urow[s]);
            }
        }
        solu_b[(size_t)(b * NG + gbase + r) * 64 + lane] =
            (unsigned)f2bf(a0) | ((unsigned)f2bf(a1) << 16);
    }
}

// ---------------- Kernel D: fused GRU via MFMA (64-row tiles) ----------------
__global__ __launch_bounds__(512) void gru_mfma(
        const ushort* __restrict__ x_b,
        const float* __restrict__ h_in,
        const ushort* __restrict__ wih_b, const ushort* __restrict__ whh_b,
        const float* __restrict__ bih, const float* __restrict__ bhh,
        float* __restrict__ out0, float* __restrict__ out1) {
    __shared__ __align__(16) ushort X[64 * 128];
    __shared__ __align__(16) ushort H[64 * 128];
    const int tid = threadIdx.x;
    const int rowbase = blockIdx.x * 64;

    {
#pragma unroll
        for (int i2 = 0; i2 < 2; ++i2) {
            const int i = tid + i2 * 512;
            const int r = i >> 4, kc = i & 15;
            us8 xv = *(const us8*)&x_b[(size_t)(rowbase + r) * NE + kc * 8];
            *(us8*)&X[(r * 16 + (kc ^ (r & 7))) * 8] = xv;
            const float4* h4 = (const float4*)(h_in + (size_t)(rowbase + r) * NE);
            const float4 f0 = h4[kc * 2], f1 = h4[kc * 2 + 1];
            us8 hv;
            hv[0] = f2bf(f0.x); hv[1] = f2bf(f0.y); hv[2] = f2bf(f0.z); hv[3] = f2bf(f0.w);
            hv[4] = f2bf(f1.x); hv[5] = f2bf(f1.y); hv[6] = f2bf(f1.z); hv[7] = f2bf(f1.w);
            *(us8*)&H[(r * 16 + (kc ^ (r & 7))) * 8] = hv;
        }
    }
    __syncthreads();

    const int w = tid >> 6, l = tid & 63;
    const int lr = l & 15, lg = l >> 4;
    const int j = w * 16 + lr;

    f32x4 acc[4][6] = {};
#pragma unroll
    for (int ks = 0; ks < 4; ++ks) {
        bf16x8 bb[6];
#pragma unroll
        for (int g = 0; g < 3; ++g) {
            bb[g]     = *(const bf16x8*)&wih_b[(size_t)(g * 128 + j) * 128 + ks * 32 + lg * 8];
            bb[g + 3] = *(const bf16x8*)&whh_b[(size_t)(g * 128 + j) * 128 + ks * 32 + lg * 8];
        }
#pragma unroll
        for (int mf = 0; mf < 4; ++mf) {
            const int r = mf * 16 + lr;
            const int c = (r * 16 + ((ks * 4 + lg) ^ (r & 7))) * 8;
            const bf16x8 ax = *(const bf16x8*)&X[c];
            const bf16x8 ah = *(const bf16x8*)&H[c];
#pragma unroll
            for (int g = 0; g < 3; ++g) {
                acc[mf][g]     = __builtin_amdgcn_mfma_f32_16x16x32_bf16(ax, bb[g],     acc[mf][g],     0, 0, 0);
                acc[mf][g + 3] = __builtin_amdgcn_mfma_f32_16x16x32_bf16(ah, bb[g + 3], acc[mf][g + 3], 0, 0, 0);
            }
        }
    }

    const float bi0 = bih[j], bi1 = bih[128 + j], bi2 = bih[256 + j];
    const float bh0 = bhh[j], bh1 = bhh[128 + j], bh2 = bhh[256 + j];
#pragma unroll
    for (int mf = 0; mf < 4; ++mf) {
#pragma unroll
        for (int q = 0; q < 4; ++q) {
            const int row = rowbase + mf * 16 + lg * 4 + q;
            const float ir = acc[mf][0][q] + bi0;
            const float iz = acc[mf][1][q] + bi1;
            const float in_ = acc[mf][2][q] + bi2;
            const float hr = acc[mf][3][q] + bh0;
            const float hz = acc[mf][4][q] + bh1;
            const float hn = acc[mf][5][q] + bh2;
            const float rr = 1.f / (1.f + expf(-(ir + hr)));
            const float zz = 1.f / (1.f + expf(-(iz + hz)));
            const float nn = tanhf(in_ + rr * hn);
            const float hv = h_in[(size_t)row * NE + j];
            const float nv = (1.f - zz) * nn + zz * hv;
            const size_t o = (size_t)row * NE + j;
            out1[o] = nv;
            out0[o] = (nv > 0.f) ? nv : expm1f(nv);
        }
    }
}

extern "C" void kernel_launch(void* const* d_in, const int* in_sizes, int n_in,
                              void* d_out, int out_size, void* d_ws, size_t ws_size,
                              hipStream_t stream) {
    const float* ne    = (const float*)d_in[0];
    const int*   sol   = (const int*)d_in[1];
    const float* costs = (const float*)d_in[2];
    const float* dist  = (const float*)d_in[3];
    const float* old_h = (const float*)d_in[4];
    const float* Wq    = (const float*)d_in[5];
    const float* Wk    = (const float*)d_in[6];
    const float* m1w   = (const float*)d_in[7];
    const float* m1b   = (const float*)d_in[8];
    const float* m2w   = (const float*)d_in[9];
    const float* m2b   = (const float*)d_in[10];
    const float* nhw   = (const float*)d_in[11];
    const float* wih   = (const float*)d_in[12];
    const float* whh   = (const float*)d_in[13];
    const float* bih   = (const float*)d_in[14];
    const float* bhh   = (const float*)d_in[15];

    float* out0 = (float*)d_out;
    float* out1 = out0 + (size_t)NB * NG * NE;

    // workspace layout (16B aligned)
    ushort*   QKb       = (ushort*)d_ws;                               // 16.384 MB
    ushort*   ne_b      = QKb + (size_t)NB * NG * 256;                 // 8.192 MB
    int2*     edge_pack = (int2*)(ne_b + (size_t)NB * NG * NE);        // 2.56 MB
    unsigned* solu_b    = (unsigned*)(edge_pack + (size_t)NS * NB * NG);// 8.192 MB
    ushort*   wih_b     = (ushort*)(solu_b + (size_t)NB * NG * 64);    // 96 KB
    ushort*   whh_b     = wih_b + 384 * 128;                           // 96 KB

    qk_prep<<<250 + 625 + 24, 512, 0, stream>>>(
        ne, sol, dist, Wq, Wk, wih, whh,
        QKb, ne_b, edge_pack, wih_b, whh_b);
    score_agg<<<4000, 256, 0, stream>>>(
        edge_pack, costs, QKb, ne_b, m1w, m1b, m2w, m2b, nhw, solu_b);
    gru_mfma<<<(NB * NG) / 64, 512, 0, stream>>>(
        (const ushort*)solu_b, old_h, wih_b, whh_b, bih, bhh, out0, out1);
}

// Round 16
// 84.476 us; speedup vs baseline: 1.4444x; 1.0157x over previous
//
#include <hip/hip_runtime.h>
#include <math.h>

#define NS 10
#define NB 32
#define NG 1000
#define NE 128
#define NH 8
#define MSH 16

typedef __bf16 bf16x8 __attribute__((ext_vector_type(8)));
typedef float f32x4 __attribute__((ext_vector_type(4)));
typedef unsigned short ushort;
typedef ushort us8 __attribute__((ext_vector_type(8)));

__device__ __forceinline__ ushort f2bf(float f) {
    union { float f; unsigned u; } c; c.f = f;
    unsigned r = c.u + 0x7FFFu + ((c.u >> 16) & 1u);
    return (ushort)(r >> 16);
}
__device__ __forceinline__ float bflo(unsigned u) {
    union { unsigned v; float f; } c; c.v = u << 16; return c.f;
}
__device__ __forceinline__ float bfhi(unsigned u) {
    union { unsigned v; float f; } c; c.v = u & 0xFFFF0000u; return c.f;
}
__device__ __forceinline__ float asf(int i) {
    union { int i; float f; } c; c.i = i; return c.f;
}
__device__ __forceinline__ int asi(float f) {
    union { float f; int i; } c; c.f = f; return c.i;
}
__device__ __forceinline__ float dot8(uint4 q, uint4 k) {
    return bflo(q.x) * bflo(k.x) + bfhi(q.x) * bfhi(k.x)
         + bflo(q.y) * bflo(k.y) + bfhi(q.y) * bfhi(k.y)
         + bflo(q.z) * bflo(k.z) + bfhi(q.z) * bfhi(k.z)
         + bflo(q.w) * bflo(k.w) + bfhi(q.w) * bfhi(k.w);
}

// ---------------- Kernel A: QK GEMM (blocks<250, 128-row tiles) + scatter + wcvt
__global__ __launch_bounds__(512) void qk_prep(
        const float* __restrict__ ne,
        const int* __restrict__ sol, const float* __restrict__ dist,
        const float* __restrict__ Wq, const float* __restrict__ Wk,
        const float* __restrict__ wih, const float* __restrict__ whh,
        ushort* __restrict__ QKb, ushort* __restrict__ ne_b,
        int2* __restrict__ edge_pack,
        ushort* __restrict__ wih_b, ushort* __restrict__ whh_b) {
    const int tid = threadIdx.x;
    if (blockIdx.x >= 250) {
        const int bid2 = blockIdx.x - 250;
        if (bid2 < 625) {
            // edge_pack scatter: 625*512 = 320000 edges
            const int gidx = bid2 * 512 + tid;         // (s*NB+b)*NG + t
            const int sb = gidx / NG;
            const int t = gidx - sb * NG;
            const int* srow = sol + (size_t)sb * NG;
            const int src = srow[t];
            const int tn = (t + 1 == NG) ? 0 : t + 1;
            const int dst = srow[tn];
            const int b = sb & 31;                     // NB = 32
            const float ev = dist[(size_t)(b * NG + src) * NG + dst];
            edge_pack[(size_t)sb * NG + src] = make_int2(dst, asi(ev));
        } else {
            const int wt = (bid2 - 625) * 512 + tid;   // 12288 chunk threads
            const int e = wt * 8;                      // [0, 98304)
            const float* src = (e < 49152) ? wih : whh;
            ushort* dst = (e < 49152) ? wih_b : whh_b;
            const int off = (e < 49152) ? e : e - 49152;
            const float4 f0 = ((const float4*)(src + off))[0];
            const float4 f1 = ((const float4*)(src + off))[1];
            us8 v;
            v[0] = f2bf(f0.x); v[1] = f2bf(f0.y); v[2] = f2bf(f0.z); v[3] = f2bf(f0.w);
            v[4] = f2bf(f1.x); v[5] = f2bf(f1.y); v[6] = f2bf(f1.z); v[7] = f2bf(f1.w);
            *(us8*)(dst + off) = v;
        }
        return;
    }

    __shared__ __align__(16) ushort A[128 * 128];   // 32 KB
    const int rowbase = blockIdx.x * 128;
    {
#pragma unroll
        for (int i2 = 0; i2 < 4; ++i2) {
            const int i = tid + i2 * 512;
            const int r = i >> 4, kc = i & 15;
            const float4* s4 = (const float4*)(ne + (size_t)(rowbase + r) * NE);
            const float4 f0 = s4[kc * 2], f1 = s4[kc * 2 + 1];
            us8 v;
            v[0] = f2bf(f0.x); v[1] = f2bf(f0.y); v[2] = f2bf(f0.z); v[3] = f2bf(f0.w);
            v[4] = f2bf(f1.x); v[5] = f2bf(f1.y); v[6] = f2bf(f1.z); v[7] = f2bf(f1.w);
            *(us8*)&A[(r * 16 + (kc ^ (r & 7))) * 8] = v;
            *(us8*)&ne_b[(size_t)(rowbase + r) * NE + kc * 8] = v;
        }
    }
    __syncthreads();

    const int w = tid >> 6, l = tid & 63;
    const int lr = l & 15, lg = l >> 4;

    f32x4 acc[8][2] = {};
#pragma unroll
    for (int ks = 0; ks < 4; ++ks) {
        bf16x8 a[8], b[2];
#pragma unroll
        for (int mf = 0; mf < 8; ++mf) {
            const int r = mf * 16 + lr;
            a[mf] = *(const bf16x8*)&A[(r * 16 + ((ks * 4 + lg) ^ (r & 7))) * 8];
        }
#pragma unroll
        for (int nf = 0; nf < 2; ++nf) {
            const int j = w * 32 + nf * 16 + lr;
            const float* Wrow = (j < 128) ? (Wq + (size_t)j * 128 + ks * 32 + lg * 8)
                                          : (Wk + (size_t)(j - 128) * 128 + ks * 32 + lg * 8);
            const float4 wf0 = ((const float4*)Wrow)[0];
            const float4 wf1 = ((const float4*)Wrow)[1];
            union { us8 u; bf16x8 bv; } cv;
            cv.u[0] = f2bf(wf0.x); cv.u[1] = f2bf(wf0.y); cv.u[2] = f2bf(wf0.z); cv.u[3] = f2bf(wf0.w);
            cv.u[4] = f2bf(wf1.x); cv.u[5] = f2bf(wf1.y); cv.u[6] = f2bf(wf1.z); cv.u[7] = f2bf(wf1.w);
            b[nf] = cv.bv;
        }
#pragma unroll
        for (int mf = 0; mf < 8; ++mf)
#pragma unroll
            for (int nf = 0; nf < 2; ++nf)
                acc[mf][nf] = __builtin_amdgcn_mfma_f32_16x16x32_bf16(a[mf], b[nf], acc[mf][nf], 0, 0, 0);
    }
#pragma unroll
    for (int mf = 0; mf < 8; ++mf)
#pragma unroll
        for (int nf = 0; nf < 2; ++nf)
#pragma unroll
            for (int q = 0; q < 4; ++q) {
                const int row = rowbase + mf * 16 + lg * 4 + q;
                const int col = w * 32 + nf * 16 + lr;
                QKb[(size_t)row * 256 + col] = f2bf(acc[mf][nf][q]);
            }
}

// ---------------- Kernel C: fused edge-score + softmax + aggregate ----------
// 2 rows per wave. Bijective XCD map. Q loads hoisted first; urow loads
// deferred into the merge loop; softmax computed WITHOUT max-subtraction
// (|score| <= ~10 << 88, exp-safe; deletes a 4-deep shfl chain per row).
__global__ __launch_bounds__(256) void score_agg(
        const int2* __restrict__ edge_pack, const float* __restrict__ costs,
        const ushort* __restrict__ QKb, const ushort* __restrict__ ne_b,
        const float* __restrict__ m1w, const float* __restrict__ m1b,
        const float* __restrict__ m2w, const float* __restrict__ m2b,
        const float* __restrict__ nhw,
        unsigned* __restrict__ solu_b) {
    __shared__ float w1t[2][MSH][NH];
    __shared__ float b1t[MSH][NH];
    __shared__ float w2t[MSH][NH];
    __shared__ float b2s[NH];
    __shared__ float nws[NH];
    const int tid = threadIdx.x;
    {   // m1w layout [h][e][m] -> transposed [e][m][h]
        const int h = tid >> 5, e = (tid >> 4) & 1, m = tid & 15;
        w1t[e][m][h] = m1w[tid];
        if (tid < 128) {
            const int h2 = tid >> 4, m2 = tid & 15;
            b1t[m2][h2] = m1b[tid];
            w2t[m2][h2] = m2w[tid];
        }
        if (tid < NH) { b2s[tid] = m2b[tid]; nws[tid] = nhw[tid]; }
    }
    __syncthreads();

    // bijective XCD-aware remap: 4000 blocks, 8 rows/block (2 per wave)
    const int bid = blockIdx.x;
    const int xcd = bid & 7;
    const int idx = bid >> 3;              // [0,500)
    const int b = xcd + 8 * (idx / 125);   // 4 batch-groups per XCD
    const int gbase = (idx % 125) * 8 + ((tid >> 6) << 1);
    const int lane = tid & 63;
    const int h = lane & 7;
    const int sg = lane >> 3;

    // ---- stage 0: Q rows (sequential, dependency-free -> issue first) ----
    uint4 qq[2][2];
#pragma unroll
    for (int r = 0; r < 2; ++r) {
        const uint4* Qr = (const uint4*)(QKb + (size_t)(b * NG + gbase + r) * 256);
        qq[r][0] = Qr[h * 2]; qq[r][1] = Qr[h * 2 + 1];
    }

    // ---- stage 1: fused {dst, edge} gathers ----
    int dstp[2][2]; float edgep[2][2];
#pragma unroll
    for (int r = 0; r < 2; ++r) {
        const int2 e0 = edge_pack[(size_t)(sg * NB + b) * NG + (gbase + r)];
        dstp[r][0] = e0.x; edgep[r][0] = asf(e0.y);
        dstp[r][1] = 0; edgep[r][1] = 0.f;
        if (sg < 2) {
            const int2 e1 = edge_pack[(size_t)((8 + sg) * NB + b) * NG + (gbase + r)];
            dstp[r][1] = e1.x; edgep[r][1] = asf(e1.y);
        }
    }

    // ---- stage 2: K gathers (lane-local dst; pass-1 exec-masked) ----
    uint4 kk[2][2][2];
#pragma unroll
    for (int r = 0; r < 2; ++r) {
        {
            const uint4* Kr = (const uint4*)(QKb + (size_t)(b * NG + dstp[r][0]) * 256 + 128);
            kk[r][0][0] = Kr[h * 2]; kk[r][0][1] = Kr[h * 2 + 1];
        }
        kk[r][1][0] = make_uint4(0, 0, 0, 0);
        kk[r][1][1] = make_uint4(0, 0, 0, 0);
        if (sg < 2) {
            const uint4* Kr = (const uint4*)(QKb + (size_t)(b * NG + dstp[r][1]) * 256 + 128);
            kk[r][1][0] = Kr[h * 2]; kk[r][1][1] = Kr[h * 2 + 1];
        }
    }

    // ---- stage 3: MLP + head reduce (4 independent chains) ----
    float val_p[2][2];
#pragma unroll
    for (int r = 0; r < 2; ++r)
#pragma unroll
        for (int p = 0; p < 2; ++p) {
            float dd = (dot8(qq[r][0], kk[r][p][0]) + dot8(qq[r][1], kk[r][p][1])) * 0.0625f;
            float ms2 = b2s[h];
#pragma unroll
            for (int m = 0; m < MSH; ++m) {
                float t = fmaf(dd, w1t[0][m][h], fmaf(edgep[r][p], w1t[1][m][h], b1t[m][h]));
                t = fmaxf(t, 0.f);
                ms2 = fmaf(t, w2t[m][h], ms2);
            }
            float contrib = ms2 * nws[h];
            contrib += __shfl_xor(contrib, 1);
            contrib += __shfl_xor(contrib, 2);
            contrib += __shfl_xor(contrib, 4);
            val_p[r][p] = contrib;
        }

    // ---- stages 4-6 per row: merge (+deferred urow loads), softmax, agg ----
    const float cinv = __builtin_amdgcn_rcpf(costs[((lane < NS) ? lane : 0) * NB + b]);
#pragma unroll
    for (int r = 0; r < 2; ++r) {
        const float va = __shfl(val_p[r][0], (lane & 7) * 8);
        const float vb = __shfl(val_p[r][1], (lane & 1) * 8);
        const int   da = __shfl(dstp[r][0], (lane & 7) * 8);
        const int   db = __shfl(dstp[r][1], (lane & 1) * 8);
        float v_own = ((lane < 8) ? va : vb) * cinv;
        const int d_own = (lane < 8) ? da : db;

        // merge: first-occurrence accumulates; issue urow load per broadcast d_p
        unsigned urow[NS];
        float acc = v_own;
        bool first = true;
#pragma unroll
        for (int p = 0; p < NS; ++p) {
            const int   d_p = __shfl(d_own, p);
            const float v_p = __shfl(v_own, p);
            urow[p] = ((const unsigned*)(ne_b + (size_t)(b * NG + d_p) * NE))[lane];
            const bool eq = (d_p == d_own);
            first = first && (!eq || p >= lane);
            acc += (eq && p > lane) ? v_p : 0.f;
        }
        const bool surv = (lane < NS) && first && (acc != 0.f);

        // softmax without max-shift: |acc| <= ~10, exp-safe; identical ratios
        const float e = surv ? __expf(acc) : 0.f;
        float den = e;
        den += __shfl_xor(den, 1);
        den += __shfl_xor(den, 2);
        den += __shfl_xor(den, 4);
        den += __shfl_xor(den, 8);
        const float wt_own = e * __builtin_amdgcn_rcpf(den);

        const bool any = (__ballot(surv) != 0ull);

        float a0 = 0.f, a1 = 0.f;
        if (!any) {
            const unsigned* base = (const unsigned*)(ne_b + (size_t)b * NG * NE);
            for (int n = 0; n < NG; ++n) {
                const unsigned u = base[n * 64 + lane];
                a0 += bflo(u); a1 += bfhi(u);
            }
            const float invG = 1.f / NG;
            a0 *= invG; a1 *= invG;
        } else {
#pragma unroll
            for (int s = 0; s < NS; ++s) {
                const float wt = __shfl(wt_own, s);   // 0 for dropped entries
                a0 += wt * bflo(urow[s]);
                a1 += wt * bfhi(urow[s]);
            }
        }
        solu_b[(size_t)(b * NG + gbase + r) * 64 + lane] =
            (unsigned)f2bf(a0) | ((unsigned)f2bf(a1) << 16);
    }
}

// ---------------- Kernel D: fused GRU via MFMA (64-row tiles) ----------------
// h staged twice: bf16 (MFMA A-operand) + f32 (exact z*h blend) -> no 16MB
// global re-read in the epilogue. LDS 64KB -> 2 blocks/CU.
__global__ __launch_bounds__(512) void gru_mfma(
        const ushort* __restrict__ x_b,
        const float* __restrict__ h_in,
        const ushort* __restrict__ wih_b, const ushort* __restrict__ whh_b,
        const float* __restrict__ bih, const float* __restrict__ bhh,
        float* __restrict__ out0, float* __restrict__ out1) {
    __shared__ __align__(16) ushort X[64 * 128];
    __shared__ __align__(16) ushort H[64 * 128];
    __shared__ __align__(16) float Hf[64 * 128];
    const int tid = threadIdx.x;
    const int rowbase = blockIdx.x * 64;

    {
#pragma unroll
        for (int i2 = 0; i2 < 2; ++i2) {
            const int i = tid + i2 * 512;
            const int r = i >> 4, kc = i & 15;
            us8 xv = *(const us8*)&x_b[(size_t)(rowbase + r) * NE + kc * 8];
            *(us8*)&X[(r * 16 + (kc ^ (r & 7))) * 8] = xv;
            const float4* h4 = (const float4*)(h_in + (size_t)(rowbase + r) * NE);
            const float4 f0 = h4[kc * 2], f1 = h4[kc * 2 + 1];
            ((float4*)Hf)[r * 32 + kc * 2]     = f0;
            ((float4*)Hf)[r * 32 + kc * 2 + 1] = f1;
            us8 hv;
            hv[0] = f2bf(f0.x); hv[1] = f2bf(f0.y); hv[2] = f2bf(f0.z); hv[3] = f2bf(f0.w);
            hv[4] = f2bf(f1.x); hv[5] = f2bf(f1.y); hv[6] = f2bf(f1.z); hv[7] = f2bf(f1.w);
            *(us8*)&H[(r * 16 + (kc ^ (r & 7))) * 8] = hv;
        }
    }
    __syncthreads();

    const int w = tid >> 6, l = tid & 63;
    const int lr = l & 15, lg = l >> 4;
    const int j = w * 16 + lr;

    f32x4 acc[4][6] = {};
#pragma unroll
    for (int ks = 0; ks < 4; ++ks) {
        bf16x8 bb[6];
#pragma unroll
        for (int g = 0; g < 3; ++g) {
            bb[g]     = *(const bf16x8*)&wih_b[(size_t)(g * 128 + j) * 128 + ks * 32 + lg * 8];
            bb[g + 3] = *(const bf16x8*)&whh_b[(size_t)(g * 128 + j) * 128 + ks * 32 + lg * 8];
        }
#pragma unroll
        for (int mf = 0; mf < 4; ++mf) {
            const int r = mf * 16 + lr;
            const int c = (r * 16 + ((ks * 4 + lg) ^ (r & 7))) * 8;
            const bf16x8 ax = *(const bf16x8*)&X[c];
            const bf16x8 ah = *(const bf16x8*)&H[c];
#pragma unroll
            for (int g = 0; g < 3; ++g) {
                acc[mf][g]     = __builtin_amdgcn_mfma_f32_16x16x32_bf16(ax, bb[g],     acc[mf][g],     0, 0, 0);
                acc[mf][g + 3] = __builtin_amdgcn_mfma_f32_16x16x32_bf16(ah, bb[g + 3], acc[mf][g + 3], 0, 0, 0);
            }
        }
    }

    const float bi0 = bih[j], bi1 = bih[128 + j], bi2 = bih[256 + j];
    const float bh0 = bhh[j], bh1 = bhh[128 + j], bh2 = bhh[256 + j];
#pragma unroll
    for (int mf = 0; mf < 4; ++mf) {
#pragma unroll
        for (int q = 0; q < 4; ++q) {
            const int rloc = mf * 16 + lg * 4 + q;
            const int row = rowbase + rloc;
            const float ir = acc[mf][0][q] + bi0;
            const float iz = acc[mf][1][q] + bi1;
            const float in_ = acc[mf][2][q] + bi2;
            const float hr = acc[mf][3][q] + bh0;
            const float hz = acc[mf][4][q] + bh1;
            const float hn = acc[mf][5][q] + bh2;
            const float rr = 1.f / (1.f + expf(-(ir + hr)));
            const float zz = 1.f / (1.f + expf(-(iz + hz)));
            const float nn = tanhf(in_ + rr * hn);
            const float hv = Hf[rloc * NE + j];
            const float nv = (1.f - zz) * nn + zz * hv;
            const size_t o = (size_t)row * NE + j;
            out1[o] = nv;
            out0[o] = (nv > 0.f) ? nv : expm1f(nv);
        }
    }
}

extern "C" void kernel_launch(void* const* d_in, const int* in_sizes, int n_in,
                              void* d_out, int out_size, void* d_ws, size_t ws_size,
                              hipStream_t stream) {
    const float* ne    = (const float*)d_in[0];
    const int*   sol   = (const int*)d_in[1];
    const float* costs = (const float*)d_in[2];
    const float* dist  = (const float*)d_in[3];
    const float* old_h = (const float*)d_in[4];
    const float* Wq    = (const float*)d_in[5];
    const float* Wk    = (const float*)d_in[6];
    const float* m1w   = (const float*)d_in[7];
    const float* m1b   = (const float*)d_in[8];
    const float* m2w   = (const float*)d_in[9];
    const float* m2b   = (const float*)d_in[10];
    const float* nhw   = (const float*)d_in[11];
    const float* wih   = (const float*)d_in[12];
    const float* whh   = (const float*)d_in[13];
    const float* bih   = (const float*)d_in[14];
    const float* bhh   = (const float*)d_in[15];

    float* out0 = (float*)d_out;
    float* out1 = out0 + (size_t)NB * NG * NE;

    // workspace layout (16B aligned)
    ushort*   QKb       = (ushort*)d_ws;                               // 16.384 MB
    ushort*   ne_b      = QKb + (size_t)NB * NG * 256;                 // 8.192 MB
    int2*     edge_pack = (int2*)(ne_b + (size_t)NB * NG * NE);        // 2.56 MB
    unsigned* solu_b    = (unsigned*)(edge_pack + (size_t)NS * NB * NG);// 8.192 MB
    ushort*   wih_b     = (ushort*)(solu_b + (size_t)NB * NG * 64);    // 96 KB
    ushort*   whh_b     = wih_b + 384 * 128;                           // 96 KB

    qk_prep<<<250 + 625 + 24, 512, 0, stream>>>(
        ne, sol, dist, Wq, Wk, wih, whh,
        QKb, ne_b, edge_pack, wih_b, whh_b);
    score_agg<<<4000, 256, 0, stream>>>(
        edge_pack, costs, QKb, ne_b, m1w, m1b, m2w, m2b, nhw, solu_b);
    gru_mfma<<<(NB * NG) / 64, 512, 0, stream>>>(
        (const ushort*)solu_b, old_h, wih_b, whh_b, bih, bhh, out0, out1);
}

// Round 17
// 81.640 us; speedup vs baseline: 1.4946x; 1.0347x over previous
//
#include <hip/hip_runtime.h>
#include <math.h>

#define NS 10
#define NB 32
#define NG 1000
#define NE 128
#define NH 8
#define MSH 16

typedef __bf16 bf16x8 __attribute__((ext_vector_type(8)));
typedef __bf16 bf16x2 __attribute__((ext_vector_type(2)));
typedef float f32x4 __attribute__((ext_vector_type(4)));
typedef unsigned short ushort;
typedef ushort us8 __attribute__((ext_vector_type(8)));

__device__ __forceinline__ ushort f2bf(float f) {
    union { float f; unsigned u; } c; c.f = f;
    unsigned r = c.u + 0x7FFFu + ((c.u >> 16) & 1u);
    return (ushort)(r >> 16);
}
__device__ __forceinline__ float bflo(unsigned u) {
    union { unsigned v; float f; } c; c.v = u << 16; return c.f;
}
__device__ __forceinline__ float bfhi(unsigned u) {
    union { unsigned v; float f; } c; c.v = u & 0xFFFF0000u; return c.f;
}
__device__ __forceinline__ float asf(int i) {
    union { int i; float f; } c; c.i = i; return c.f;
}
__device__ __forceinline__ int asi(float f) {
    union { float f; int i; } c; c.f = f; return c.i;
}

#if __has_builtin(__builtin_amdgcn_fdot2_f32_bf16)
__device__ __forceinline__ float dot8acc(uint4 q, uint4 k, float d) {
    union { unsigned u; bf16x2 v; } qa, ka;
    qa.u = q.x; ka.u = k.x; d = __builtin_amdgcn_fdot2_f32_bf16(qa.v, ka.v, d, false);
    qa.u = q.y; ka.u = k.y; d = __builtin_amdgcn_fdot2_f32_bf16(qa.v, ka.v, d, false);
    qa.u = q.z; ka.u = k.z; d = __builtin_amdgcn_fdot2_f32_bf16(qa.v, ka.v, d, false);
    qa.u = q.w; ka.u = k.w; d = __builtin_amdgcn_fdot2_f32_bf16(qa.v, ka.v, d, false);
    return d;
}
#else
__device__ __forceinline__ float dot8acc(uint4 q, uint4 k, float d) {
    d += bflo(q.x) * bflo(k.x) + bfhi(q.x) * bfhi(k.x)
       + bflo(q.y) * bflo(k.y) + bfhi(q.y) * bfhi(k.y)
       + bflo(q.z) * bflo(k.z) + bfhi(q.z) * bfhi(k.z)
       + bflo(q.w) * bflo(k.w) + bfhi(q.w) * bfhi(k.w);
    return d;
}
#endif

// ---------------- Kernel A: QK GEMM (blocks<250, 128-row tiles) + scatter + wcvt
__global__ __launch_bounds__(512) void qk_prep(
        const float* __restrict__ ne,
        const int* __restrict__ sol, const float* __restrict__ dist,
        const float* __restrict__ Wq, const float* __restrict__ Wk,
        const float* __restrict__ wih, const float* __restrict__ whh,
        ushort* __restrict__ QKb, ushort* __restrict__ ne_b,
        int2* __restrict__ edge_pack,
        ushort* __restrict__ wih_b, ushort* __restrict__ whh_b) {
    const int tid = threadIdx.x;
    if (blockIdx.x >= 250) {
        const int bid2 = blockIdx.x - 250;
        if (bid2 < 625) {
            // edge_pack scatter: 625*512 = 320000 edges
            const int gidx = bid2 * 512 + tid;         // (s*NB+b)*NG + t
            const int sb = gidx / NG;
            const int t = gidx - sb * NG;
            const int* srow = sol + (size_t)sb * NG;
            const int src = srow[t];
            const int tn = (t + 1 == NG) ? 0 : t + 1;
            const int dst = srow[tn];
            const int b = sb & 31;                     // NB = 32
            const float ev = dist[(size_t)(b * NG + src) * NG + dst];
            edge_pack[(size_t)sb * NG + src] = make_int2(dst, asi(ev));
        } else {
            const int wt = (bid2 - 625) * 512 + tid;   // 12288 chunk threads
            const int e = wt * 8;                      // [0, 98304)
            const float* src = (e < 49152) ? wih : whh;
            ushort* dst = (e < 49152) ? wih_b : whh_b;
            const int off = (e < 49152) ? e : e - 49152;
            const float4 f0 = ((const float4*)(src + off))[0];
            const float4 f1 = ((const float4*)(src + off))[1];
            us8 v;
            v[0] = f2bf(f0.x); v[1] = f2bf(f0.y); v[2] = f2bf(f0.z); v[3] = f2bf(f0.w);
            v[4] = f2bf(f1.x); v[5] = f2bf(f1.y); v[6] = f2bf(f1.z); v[7] = f2bf(f1.w);
            *(us8*)(dst + off) = v;
        }
        return;
    }

    __shared__ __align__(16) ushort A[128 * 128];   // 32 KB
    const int rowbase = blockIdx.x * 128;
    {
#pragma unroll
        for (int i2 = 0; i2 < 4; ++i2) {
            const int i = tid + i2 * 512;
            const int r = i >> 4, kc = i & 15;
            const float4* s4 = (const float4*)(ne + (size_t)(rowbase + r) * NE);
            const float4 f0 = s4[kc * 2], f1 = s4[kc * 2 + 1];
            us8 v;
            v[0] = f2bf(f0.x); v[1] = f2bf(f0.y); v[2] = f2bf(f0.z); v[3] = f2bf(f0.w);
            v[4] = f2bf(f1.x); v[5] = f2bf(f1.y); v[6] = f2bf(f1.z); v[7] = f2bf(f1.w);
            *(us8*)&A[(r * 16 + (kc ^ (r & 7))) * 8] = v;
            *(us8*)&ne_b[(size_t)(rowbase + r) * NE + kc * 8] = v;
        }
    }
    __syncthreads();

    const int w = tid >> 6, l = tid & 63;
    const int lr = l & 15, lg = l >> 4;

    f32x4 acc[8][2] = {};
#pragma unroll
    for (int ks = 0; ks < 4; ++ks) {
        bf16x8 a[8], b[2];
#pragma unroll
        for (int mf = 0; mf < 8; ++mf) {
            const int r = mf * 16 + lr;
            a[mf] = *(const bf16x8*)&A[(r * 16 + ((ks * 4 + lg) ^ (r & 7))) * 8];
        }
#pragma unroll
        for (int nf = 0; nf < 2; ++nf) {
            const int j = w * 32 + nf * 16 + lr;
            const float* Wrow = (j < 128) ? (Wq + (size_t)j * 128 + ks * 32 + lg * 8)
                                          : (Wk + (size_t)(j - 128) * 128 + ks * 32 + lg * 8);
            const float4 wf0 = ((const float4*)Wrow)[0];
            const float4 wf1 = ((const float4*)Wrow)[1];
            union { us8 u; bf16x8 bv; } cv;
            cv.u[0] = f2bf(wf0.x); cv.u[1] = f2bf(wf0.y); cv.u[2] = f2bf(wf0.z); cv.u[3] = f2bf(wf0.w);
            cv.u[4] = f2bf(wf1.x); cv.u[5] = f2bf(wf1.y); cv.u[6] = f2bf(wf1.z); cv.u[7] = f2bf(wf1.w);
            b[nf] = cv.bv;
        }
#pragma unroll
        for (int mf = 0; mf < 8; ++mf)
#pragma unroll
            for (int nf = 0; nf < 2; ++nf)
                acc[mf][nf] = __builtin_amdgcn_mfma_f32_16x16x32_bf16(a[mf], b[nf], acc[mf][nf], 0, 0, 0);
    }
#pragma unroll
    for (int mf = 0; mf < 8; ++mf)
#pragma unroll
        for (int nf = 0; nf < 2; ++nf)
#pragma unroll
            for (int q = 0; q < 4; ++q) {
                const int row = rowbase + mf * 16 + lg * 4 + q;
                const int col = w * 32 + nf * 16 + lr;
                QKb[(size_t)row * 256 + col] = f2bf(acc[mf][nf][q]);
            }
}

// ---------------- Kernel C: fused edge-score + softmax + aggregate ----------
// 2 rows per wave. Bijective XCD map. Q loads hoisted first; urow loads
// deferred into the merge loop; softmax without max-shift (|score|<=~10).
// Dots via v_dot2_f32_bf16 when available (32 -> 4 VALU per dot8).
__global__ __launch_bounds__(256) void score_agg(
        const int2* __restrict__ edge_pack, const float* __restrict__ costs,
        const ushort* __restrict__ QKb, const ushort* __restrict__ ne_b,
        const float* __restrict__ m1w, const float* __restrict__ m1b,
        const float* __restrict__ m2w, const float* __restrict__ m2b,
        const float* __restrict__ nhw,
        unsigned* __restrict__ solu_b) {
    __shared__ float w1t[2][MSH][NH];
    __shared__ float b1t[MSH][NH];
    __shared__ float w2t[MSH][NH];
    __shared__ float b2s[NH];
    __shared__ float nws[NH];
    const int tid = threadIdx.x;
    {   // m1w layout [h][e][m] -> transposed [e][m][h]
        const int h = tid >> 5, e = (tid >> 4) & 1, m = tid & 15;
        w1t[e][m][h] = m1w[tid];
        if (tid < 128) {
            const int h2 = tid >> 4, m2 = tid & 15;
            b1t[m2][h2] = m1b[tid];
            w2t[m2][h2] = m2w[tid];
        }
        if (tid < NH) { b2s[tid] = m2b[tid]; nws[tid] = nhw[tid]; }
    }
    __syncthreads();

    // bijective XCD-aware remap: 4000 blocks, 8 rows/block (2 per wave)
    const int bid = blockIdx.x;
    const int xcd = bid & 7;
    const int idx = bid >> 3;              // [0,500)
    const int b = xcd + 8 * (idx / 125);   // 4 batch-groups per XCD
    const int gbase = (idx % 125) * 8 + ((tid >> 6) << 1);
    const int lane = tid & 63;
    const int h = lane & 7;
    const int sg = lane >> 3;

    // ---- stage 0: Q rows (sequential, dependency-free -> issue first) ----
    uint4 qq[2][2];
#pragma unroll
    for (int r = 0; r < 2; ++r) {
        const uint4* Qr = (const uint4*)(QKb + (size_t)(b * NG + gbase + r) * 256);
        qq[r][0] = Qr[h * 2]; qq[r][1] = Qr[h * 2 + 1];
    }

    // ---- stage 1: fused {dst, edge} gathers ----
    int dstp[2][2]; float edgep[2][2];
#pragma unroll
    for (int r = 0; r < 2; ++r) {
        const int2 e0 = edge_pack[(size_t)(sg * NB + b) * NG + (gbase + r)];
        dstp[r][0] = e0.x; edgep[r][0] = asf(e0.y);
        dstp[r][1] = 0; edgep[r][1] = 0.f;
        if (sg < 2) {
            const int2 e1 = edge_pack[(size_t)((8 + sg) * NB + b) * NG + (gbase + r)];
            dstp[r][1] = e1.x; edgep[r][1] = asf(e1.y);
        }
    }

    // ---- stage 2: K gathers (lane-local dst; pass-1 exec-masked) ----
    uint4 kk[2][2][2];
#pragma unroll
    for (int r = 0; r < 2; ++r) {
        {
            const uint4* Kr = (const uint4*)(QKb + (size_t)(b * NG + dstp[r][0]) * 256 + 128);
            kk[r][0][0] = Kr[h * 2]; kk[r][0][1] = Kr[h * 2 + 1];
        }
        kk[r][1][0] = make_uint4(0, 0, 0, 0);
        kk[r][1][1] = make_uint4(0, 0, 0, 0);
        if (sg < 2) {
            const uint4* Kr = (const uint4*)(QKb + (size_t)(b * NG + dstp[r][1]) * 256 + 128);
            kk[r][1][0] = Kr[h * 2]; kk[r][1][1] = Kr[h * 2 + 1];
        }
    }

    // ---- stage 3: MLP + head reduce (4 independent chains) ----
    float val_p[2][2];
#pragma unroll
    for (int r = 0; r < 2; ++r)
#pragma unroll
        for (int p = 0; p < 2; ++p) {
            float dd = dot8acc(qq[r][1], kk[r][p][1],
                               dot8acc(qq[r][0], kk[r][p][0], 0.f)) * 0.0625f;
            float ms2 = b2s[h];
#pragma unroll
            for (int m = 0; m < MSH; ++m) {
                float t = fmaf(dd, w1t[0][m][h], fmaf(edgep[r][p], w1t[1][m][h], b1t[m][h]));
                t = fmaxf(t, 0.f);
                ms2 = fmaf(t, w2t[m][h], ms2);
            }
            float contrib = ms2 * nws[h];
            contrib += __shfl_xor(contrib, 1);
            contrib += __shfl_xor(contrib, 2);
            contrib += __shfl_xor(contrib, 4);
            val_p[r][p] = contrib;
        }

    // ---- stages 4-6 per row: merge (+deferred urow loads), softmax, agg ----
    const float cinv = __builtin_amdgcn_rcpf(costs[((lane < NS) ? lane : 0) * NB + b]);
#pragma unroll
    for (int r = 0; r < 2; ++r) {
        const float va = __shfl(val_p[r][0], (lane & 7) * 8);
        const float vb = __shfl(val_p[r][1], (lane & 1) * 8);
        const int   da = __shfl(dstp[r][0], (lane & 7) * 8);
        const int   db = __shfl(dstp[r][1], (lane & 1) * 8);
        float v_own = ((lane < 8) ? va : vb) * cinv;
        const int d_own = (lane < 8) ? da : db;

        // merge: first-occurrence accumulates; issue urow load per broadcast d_p
        unsigned urow[NS];
        float acc = v_own;
        bool first = true;
#pragma unroll
        for (int p = 0; p < NS; ++p) {
            const int   d_p = __shfl(d_own, p);
            const float v_p = __shfl(v_own, p);
            urow[p] = ((const unsigned*)(ne_b + (size_t)(b * NG + d_p) * NE))[lane];
            const bool eq = (d_p == d_own);
            first = first && (!eq || p >= lane);
            acc += (eq && p > lane) ? v_p : 0.f;
        }
        const bool surv = (lane < NS) && first && (acc != 0.f);

        // softmax without max-shift: |acc| <= ~10, exp-safe; identical ratios
        const float e = surv ? __expf(acc) : 0.f;
        float den = e;
        den += __shfl_xor(den, 1);
        den += __shfl_xor(den, 2);
        den += __shfl_xor(den, 4);
        den += __shfl_xor(den, 8);
        const float wt_own = e * __builtin_amdgcn_rcpf(den);

        const bool any = (__ballot(surv) != 0ull);

        float a0 = 0.f, a1 = 0.f;
        if (!any) {
            const unsigned* base = (const unsigned*)(ne_b + (size_t)b * NG * NE);
            for (int n = 0; n < NG; ++n) {
                const unsigned u = base[n * 64 + lane];
                a0 += bflo(u); a1 += bfhi(u);
            }
            const float invG = 1.f / NG;
            a0 *= invG; a1 *= invG;
        } else {
#pragma unroll
            for (int s = 0; s < NS; ++s) {
                const float wt = __shfl(wt_own, s);   // 0 for dropped entries
                a0 += wt * bflo(urow[s]);
                a1 += wt * bfhi(urow[s]);
            }
        }
        solu_b[(size_t)(b * NG + gbase + r) * 64 + lane] =
            (unsigned)f2bf(a0) | ((unsigned)f2bf(a1) << 16);
    }
}

// ---------------- Kernel D: fused GRU via MFMA (64-row tiles) ----------------
// h staged twice: bf16 (MFMA A-operand) + f32 (exact z*h blend).
__global__ __launch_bounds__(512) void gru_mfma(
        const ushort* __restrict__ x_b,
        const float* __restrict__ h_in,
        const ushort* __restrict__ wih_b, const ushort* __restrict__ whh_b,
        const float* __restrict__ bih, const float* __restrict__ bhh,
        float* __restrict__ out0, float* __restrict__ out1) {
    __shared__ __align__(16) ushort X[64 * 128];
    __shared__ __align__(16) ushort H[64 * 128];
    __shared__ __align__(16) float Hf[64 * 128];
    const int tid = threadIdx.x;
    const int rowbase = blockIdx.x * 64;

    {
#pragma unroll
        for (int i2 = 0; i2 < 2; ++i2) {
            const int i = tid + i2 * 512;
            const int r = i >> 4, kc = i & 15;
            us8 xv = *(const us8*)&x_b[(size_t)(rowbase + r) * NE + kc * 8];
            *(us8*)&X[(r * 16 + (kc ^ (r & 7))) * 8] = xv;
            const float4* h4 = (const float4*)(h_in + (size_t)(rowbase + r) * NE);
            const float4 f0 = h4[kc * 2], f1 = h4[kc * 2 + 1];
            ((float4*)Hf)[r * 32 + kc * 2]     = f0;
            ((float4*)Hf)[r * 32 + kc * 2 + 1] = f1;
            us8 hv;
            hv[0] = f2bf(f0.x); hv[1] = f2bf(f0.y); hv[2] = f2bf(f0.z); hv[3] = f2bf(f0.w);
            hv[4] = f2bf(f1.x); hv[5] = f2bf(f1.y); hv[6] = f2bf(f1.z); hv[7] = f2bf(f1.w);
            *(us8*)&H[(r * 16 + (kc ^ (r & 7))) * 8] = hv;
        }
    }
    __syncthreads();

    const int w = tid >> 6, l = tid & 63;
    const int lr = l & 15, lg = l >> 4;
    const int j = w * 16 + lr;

    f32x4 acc[4][6] = {};
#pragma unroll
    for (int ks = 0; ks < 4; ++ks) {
        bf16x8 bb[6];
#pragma unroll
        for (int g = 0; g < 3; ++g) {
            bb[g]     = *(const bf16x8*)&wih_b[(size_t)(g * 128 + j) * 128 + ks * 32 + lg * 8];
            bb[g + 3] = *(const bf16x8*)&whh_b[(size_t)(g * 128 + j) * 128 + ks * 32 + lg * 8];
        }
#pragma unroll
        for (int mf = 0; mf < 4; ++mf) {
            const int r = mf * 16 + lr;
            const int c = (r * 16 + ((ks * 4 + lg) ^ (r & 7))) * 8;
            const bf16x8 ax = *(const bf16x8*)&X[c];
            const bf16x8 ah = *(const bf16x8*)&H[c];
#pragma unroll
            for (int g = 0; g < 3; ++g) {
                acc[mf][g]     = __builtin_amdgcn_mfma_f32_16x16x32_bf16(ax, bb[g],     acc[mf][g],     0, 0, 0);
                acc[mf][g + 3] = __builtin_amdgcn_mfma_f32_16x16x32_bf16(ah, bb[g + 3], acc[mf][g + 3], 0, 0, 0);
            }
        }
    }

    const float bi0 = bih[j], bi1 = bih[128 + j], bi2 = bih[256 + j];
    const float bh0 = bhh[j], bh1 = bhh[128 + j], bh2 = bhh[256 + j];
#pragma unroll
    for (int mf = 0; mf < 4; ++mf) {
#pragma unroll
        for (int q = 0; q < 4; ++q) {
            const int rloc = mf * 16 + lg * 4 + q;
            const int row = rowbase + rloc;
            const float ir = acc[mf][0][q] + bi0;
            const float iz = acc[mf][1][q] + bi1;
            const float in_ = acc[mf][2][q] + bi2;
            const float hr = acc[mf][3][q] + bh0;
            const float hz = acc[mf][4][q] + bh1;
            const float hn = acc[mf][5][q] + bh2;
            const float rr = 1.f / (1.f + expf(-(ir + hr)));
            const float zz = 1.f / (1.f + expf(-(iz + hz)));
            const float nn = tanhf(in_ + rr * hn);
            const float hv = Hf[rloc * NE + j];
            const float nv = (1.f - zz) * nn + zz * hv;
            const size_t o = (size_t)row * NE + j;
            out1[o] = nv;
            out0[o] = (nv > 0.f) ? nv : expm1f(nv);
        }
    }
}

extern "C" void kernel_launch(void* const* d_in, const int* in_sizes, int n_in,
                              void* d_out, int out_size, void* d_ws, size_t ws_size,
                              hipStream_t stream) {
    const float* ne    = (const float*)d_in[0];
    const int*   sol   = (const int*)d_in[1];
    const float* costs = (const float*)d_in[2];
    const float* dist  = (const float*)d_in[3];
    const float* old_h = (const float*)d_in[4];
    const float* Wq    = (const float*)d_in[5];
    const float* Wk    = (const float*)d_in[6];
    const float* m1w   = (const float*)d_in[7];
    const float* m1b   = (const float*)d_in[8];
    const float* m2w   = (const float*)d_in[9];
    const float* m2b   = (const float*)d_in[10];
    const float* nhw   = (const float*)d_in[11];
    const float* wih   = (const float*)d_in[12];
    const float* whh   = (const float*)d_in[13];
    const float* bih   = (const float*)d_in[14];
    const float* bhh   = (const float*)d_in[15];

    float* out0 = (float*)d_out;
    float* out1 = out0 + (size_t)NB * NG * NE;

    // workspace layout (16B aligned)
    ushort*   QKb       = (ushort*)d_ws;                               // 16.384 MB
    ushort*   ne_b      = QKb + (size_t)NB * NG * 256;                 // 8.192 MB
    int2*     edge_pack = (int2*)(ne_b + (size_t)NB * NG * NE);        // 2.56 MB
    unsigned* solu_b    = (unsigned*)(edge_pack + (size_t)NS * NB * NG);// 8.192 MB
    ushort*   wih_b     = (ushort*)(solu_b + (size_t)NB * NG * 64);    // 96 KB
    ushort*   whh_b     = wih_b + 384 * 128;                           // 96 KB

    qk_prep<<<250 + 625 + 24, 512, 0, stream>>>(
        ne, sol, dist, Wq, Wk, wih, whh,
        QKb, ne_b, edge_pack, wih_b, whh_b);
    score_agg<<<4000, 256, 0, stream>>>(
        edge_pack, costs, QKb, ne_b, m1w, m1b, m2w, m2b, nhw, solu_b);
    gru_mfma<<<(NB * NG) / 64, 512, 0, stream>>>(
        (const ushort*)solu_b, old_h, wih_b, whh_b, bih, bhh, out0, out1);
}

// Round 18
// 81.546 us; speedup vs baseline: 1.4964x; 1.0012x over previous
//
#include <hip/hip_runtime.h>
#include <math.h>

#define NS 10
#define NB 32
#define NG 1000
#define NE 128
#define NH 8
#define MSH 16

typedef __bf16 bf16x8 __attribute__((ext_vector_type(8)));
typedef __bf16 bf16x2 __attribute__((ext_vector_type(2)));
typedef float f32x4 __attribute__((ext_vector_type(4)));
typedef unsigned short ushort;
typedef ushort us8 __attribute__((ext_vector_type(8)));

__device__ __forceinline__ ushort f2bf(float f) {
    union { float f; unsigned u; } c; c.f = f;
    unsigned r = c.u + 0x7FFFu + ((c.u >> 16) & 1u);
    return (ushort)(r >> 16);
}
__device__ __forceinline__ float bflo(unsigned u) {
    union { unsigned v; float f; } c; c.v = u << 16; return c.f;
}
__device__ __forceinline__ float bfhi(unsigned u) {
    union { unsigned v; float f; } c; c.v = u & 0xFFFF0000u; return c.f;
}
__device__ __forceinline__ float asf(int i) {
    union { int i; float f; } c; c.i = i; return c.f;
}
__device__ __forceinline__ int asi(float f) {
    union { float f; int i; } c; c.f = f; return c.i;
}

#if __has_builtin(__builtin_amdgcn_fdot2_f32_bf16)
__device__ __forceinline__ float dot8acc(uint4 q, uint4 k, float d) {
    union { unsigned u; bf16x2 v; } qa, ka;
    qa.u = q.x; ka.u = k.x; d = __builtin_amdgcn_fdot2_f32_bf16(qa.v, ka.v, d, false);
    qa.u = q.y; ka.u = k.y; d = __builtin_amdgcn_fdot2_f32_bf16(qa.v, ka.v, d, false);
    qa.u = q.z; ka.u = k.z; d = __builtin_amdgcn_fdot2_f32_bf16(qa.v, ka.v, d, false);
    qa.u = q.w; ka.u = k.w; d = __builtin_amdgcn_fdot2_f32_bf16(qa.v, ka.v, d, false);
    return d;
}
#else
__device__ __forceinline__ float dot8acc(uint4 q, uint4 k, float d) {
    d += bflo(q.x) * bflo(k.x) + bfhi(q.x) * bfhi(k.x)
       + bflo(q.y) * bflo(k.y) + bfhi(q.y) * bfhi(k.y)
       + bflo(q.z) * bflo(k.z) + bfhi(q.z) * bfhi(k.z)
       + bflo(q.w) * bflo(k.w) + bfhi(q.w) * bfhi(k.w);
    return d;
}
#endif

// ---------------- Kernel A: QK GEMM (blocks<250, 128-row tiles) + scatter + wcvt
__global__ __launch_bounds__(512) void qk_prep(
        const float* __restrict__ ne,
        const int* __restrict__ sol, const float* __restrict__ dist,
        const float* __restrict__ Wq, const float* __restrict__ Wk,
        const float* __restrict__ wih, const float* __restrict__ whh,
        ushort* __restrict__ QKb, ushort* __restrict__ ne_b,
        int2* __restrict__ edge_pack,
        ushort* __restrict__ wih_b, ushort* __restrict__ whh_b) {
    const int tid = threadIdx.x;
    if (blockIdx.x >= 250) {
        const int bid2 = blockIdx.x - 250;
        if (bid2 < 625) {
            // edge_pack scatter: 625*512 = 320000 edges
            const int gidx = bid2 * 512 + tid;         // (s*NB+b)*NG + t
            const int sb = gidx / NG;
            const int t = gidx - sb * NG;
            const int* srow = sol + (size_t)sb * NG;
            const int src = srow[t];
            const int tn = (t + 1 == NG) ? 0 : t + 1;
            const int dst = srow[tn];
            const int b = sb & 31;                     // NB = 32
            const float ev = dist[(size_t)(b * NG + src) * NG + dst];
            edge_pack[(size_t)sb * NG + src] = make_int2(dst, asi(ev));
        } else {
            const int wt = (bid2 - 625) * 512 + tid;   // 12288 chunk threads
            const int e = wt * 8;                      // [0, 98304)
            const float* src = (e < 49152) ? wih : whh;
            ushort* dst = (e < 49152) ? wih_b : whh_b;
            const int off = (e < 49152) ? e : e - 49152;
            const float4 f0 = ((const float4*)(src + off))[0];
            const float4 f1 = ((const float4*)(src + off))[1];
            us8 v;
            v[0] = f2bf(f0.x); v[1] = f2bf(f0.y); v[2] = f2bf(f0.z); v[3] = f2bf(f0.w);
            v[4] = f2bf(f1.x); v[5] = f2bf(f1.y); v[6] = f2bf(f1.z); v[7] = f2bf(f1.w);
            *(us8*)(dst + off) = v;
        }
        return;
    }

    __shared__ __align__(16) ushort A[128 * 128];   // 32 KB
    const int rowbase = blockIdx.x * 128;
    {
#pragma unroll
        for (int i2 = 0; i2 < 4; ++i2) {
            const int i = tid + i2 * 512;
            const int r = i >> 4, kc = i & 15;
            const float4* s4 = (const float4*)(ne + (size_t)(rowbase + r) * NE);
            const float4 f0 = s4[kc * 2], f1 = s4[kc * 2 + 1];
            us8 v;
            v[0] = f2bf(f0.x); v[1] = f2bf(f0.y); v[2] = f2bf(f0.z); v[3] = f2bf(f0.w);
            v[4] = f2bf(f1.x); v[5] = f2bf(f1.y); v[6] = f2bf(f1.z); v[7] = f2bf(f1.w);
            *(us8*)&A[(r * 16 + (kc ^ (r & 7))) * 8] = v;
            *(us8*)&ne_b[(size_t)(rowbase + r) * NE + kc * 8] = v;
        }
    }
    __syncthreads();

    const int w = tid >> 6, l = tid & 63;
    const int lr = l & 15, lg = l >> 4;

    f32x4 acc[8][2] = {};
#pragma unroll
    for (int ks = 0; ks < 4; ++ks) {
        bf16x8 a[8], b[2];
#pragma unroll
        for (int mf = 0; mf < 8; ++mf) {
            const int r = mf * 16 + lr;
            a[mf] = *(const bf16x8*)&A[(r * 16 + ((ks * 4 + lg) ^ (r & 7))) * 8];
        }
#pragma unroll
        for (int nf = 0; nf < 2; ++nf) {
            const int j = w * 32 + nf * 16 + lr;
            const float* Wrow = (j < 128) ? (Wq + (size_t)j * 128 + ks * 32 + lg * 8)
                                          : (Wk + (size_t)(j - 128) * 128 + ks * 32 + lg * 8);
            const float4 wf0 = ((const float4*)Wrow)[0];
            const float4 wf1 = ((const float4*)Wrow)[1];
            union { us8 u; bf16x8 bv; } cv;
            cv.u[0] = f2bf(wf0.x); cv.u[1] = f2bf(wf0.y); cv.u[2] = f2bf(wf0.z); cv.u[3] = f2bf(wf0.w);
            cv.u[4] = f2bf(wf1.x); cv.u[5] = f2bf(wf1.y); cv.u[6] = f2bf(wf1.z); cv.u[7] = f2bf(wf1.w);
            b[nf] = cv.bv;
        }
#pragma unroll
        for (int mf = 0; mf < 8; ++mf)
#pragma unroll
            for (int nf = 0; nf < 2; ++nf)
                acc[mf][nf] = __builtin_amdgcn_mfma_f32_16x16x32_bf16(a[mf], b[nf], acc[mf][nf], 0, 0, 0);
    }
#pragma unroll
    for (int mf = 0; mf < 8; ++mf)
#pragma unroll
        for (int nf = 0; nf < 2; ++nf)
#pragma unroll
            for (int q = 0; q < 4; ++q) {
                const int row = rowbase + mf * 16 + lg * 4 + q;
                const int col = w * 32 + nf * 16 + lr;
                QKb[(size_t)row * 256 + col] = f2bf(acc[mf][nf][q]);
            }
}

// ---------------- Kernel C: fused edge-score + softmax + aggregate ----------
// 2 rows per wave. Bijective XCD map. Q loads hoisted; edge_pack loads for
// BOTH rows fused into one int4 (rows adjacent, 16B-aligned) -> 2 gathers at
// the chain head instead of 4; urow deferred; softmax without max-shift;
// dots via v_dot2_f32_bf16.
__global__ __launch_bounds__(256) void score_agg(
        const int2* __restrict__ edge_pack, const float* __restrict__ costs,
        const ushort* __restrict__ QKb, const ushort* __restrict__ ne_b,
        const float* __restrict__ m1w, const float* __restrict__ m1b,
        const float* __restrict__ m2w, const float* __restrict__ m2b,
        const float* __restrict__ nhw,
        unsigned* __restrict__ solu_b) {
    __shared__ float w1t[2][MSH][NH];
    __shared__ float b1t[MSH][NH];
    __shared__ float w2t[MSH][NH];
    __shared__ float b2s[NH];
    __shared__ float nws[NH];
    const int tid = threadIdx.x;
    {   // m1w layout [h][e][m] -> transposed [e][m][h]
        const int h = tid >> 5, e = (tid >> 4) & 1, m = tid & 15;
        w1t[e][m][h] = m1w[tid];
        if (tid < 128) {
            const int h2 = tid >> 4, m2 = tid & 15;
            b1t[m2][h2] = m1b[tid];
            w2t[m2][h2] = m2w[tid];
        }
        if (tid < NH) { b2s[tid] = m2b[tid]; nws[tid] = nhw[tid]; }
    }
    __syncthreads();

    // bijective XCD-aware remap: 4000 blocks, 8 rows/block (2 per wave)
    const int bid = blockIdx.x;
    const int xcd = bid & 7;
    const int idx = bid >> 3;              // [0,500)
    const int b = xcd + 8 * (idx / 125);   // 4 batch-groups per XCD
    const int gbase = (idx % 125) * 8 + ((tid >> 6) << 1);
    const int lane = tid & 63;
    const int h = lane & 7;
    const int sg = lane >> 3;

    // ---- stage 0: Q rows (sequential, dependency-free -> issue first) ----
    uint4 qq[2][2];
#pragma unroll
    for (int r = 0; r < 2; ++r) {
        const uint4* Qr = (const uint4*)(QKb + (size_t)(b * NG + gbase + r) * 256);
        qq[r][0] = Qr[h * 2]; qq[r][1] = Qr[h * 2 + 1];
    }

    // ---- stage 1: fused {dst, edge} gathers: both rows in one int4 ----
    int dstp[2][2]; float edgep[2][2];
    {
        const int4 e01 = *(const int4*)&edge_pack[(size_t)(sg * NB + b) * NG + gbase];
        dstp[0][0] = e01.x; edgep[0][0] = asf(e01.y);
        dstp[1][0] = e01.z; edgep[1][0] = asf(e01.w);
        dstp[0][1] = 0; edgep[0][1] = 0.f;
        dstp[1][1] = 0; edgep[1][1] = 0.f;
        if (sg < 2) {
            const int4 e23 = *(const int4*)&edge_pack[(size_t)((8 + sg) * NB + b) * NG + gbase];
            dstp[0][1] = e23.x; edgep[0][1] = asf(e23.y);
            dstp[1][1] = e23.z; edgep[1][1] = asf(e23.w);
        }
    }

    // ---- stage 2: K gathers (lane-local dst; pass-1 exec-masked) ----
    uint4 kk[2][2][2];
#pragma unroll
    for (int r = 0; r < 2; ++r) {
        {
            const uint4* Kr = (const uint4*)(QKb + (size_t)(b * NG + dstp[r][0]) * 256 + 128);
            kk[r][0][0] = Kr[h * 2]; kk[r][0][1] = Kr[h * 2 + 1];
        }
        kk[r][1][0] = make_uint4(0, 0, 0, 0);
        kk[r][1][1] = make_uint4(0, 0, 0, 0);
        if (sg < 2) {
            const uint4* Kr = (const uint4*)(QKb + (size_t)(b * NG + dstp[r][1]) * 256 + 128);
            kk[r][1][0] = Kr[h * 2]; kk[r][1][1] = Kr[h * 2 + 1];
        }
    }

    // ---- stage 3: MLP + head reduce (4 independent chains) ----
    float val_p[2][2];
#pragma unroll
    for (int r = 0; r < 2; ++r)
#pragma unroll
        for (int p = 0; p < 2; ++p) {
            float dd = dot8acc(qq[r][1], kk[r][p][1],
                               dot8acc(qq[r][0], kk[r][p][0], 0.f)) * 0.0625f;
            float ms2 = b2s[h];
#pragma unroll
            for (int m = 0; m < MSH; ++m) {
                float t = fmaf(dd, w1t[0][m][h], fmaf(edgep[r][p], w1t[1][m][h], b1t[m][h]));
                t = fmaxf(t, 0.f);
                ms2 = fmaf(t, w2t[m][h], ms2);
            }
            float contrib = ms2 * nws[h];
            contrib += __shfl_xor(contrib, 1);
            contrib += __shfl_xor(contrib, 2);
            contrib += __shfl_xor(contrib, 4);
            val_p[r][p] = contrib;
        }

    // ---- stages 4-6 per row: merge (+deferred urow loads), softmax, agg ----
    const float cinv = __builtin_amdgcn_rcpf(costs[((lane < NS) ? lane : 0) * NB + b]);
#pragma unroll
    for (int r = 0; r < 2; ++r) {
        const float va = __shfl(val_p[r][0], (lane & 7) * 8);
        const float vb = __shfl(val_p[r][1], (lane & 1) * 8);
        const int   da = __shfl(dstp[r][0], (lane & 7) * 8);
        const int   db = __shfl(dstp[r][1], (lane & 1) * 8);
        float v_own = ((lane < 8) ? va : vb) * cinv;
        const int d_own = (lane < 8) ? da : db;

        // merge: first-occurrence accumulates; issue urow load per broadcast d_p
        unsigned urow[NS];
        float acc = v_own;
        bool first = true;
#pragma unroll
        for (int p = 0; p < NS; ++p) {
            const int   d_p = __shfl(d_own, p);
            const float v_p = __shfl(v_own, p);
            urow[p] = ((const unsigned*)(ne_b + (size_t)(b * NG + d_p) * NE))[lane];
            const bool eq = (d_p == d_own);
            first = first && (!eq || p >= lane);
            acc += (eq && p > lane) ? v_p : 0.f;
        }
        const bool surv = (lane < NS) && first && (acc != 0.f);

        // softmax without max-shift: |acc| <= ~10, exp-safe; identical ratios
        const float e = surv ? __expf(acc) : 0.f;
        float den = e;
        den += __shfl_xor(den, 1);
        den += __shfl_xor(den, 2);
        den += __shfl_xor(den, 4);
        den += __shfl_xor(den, 8);
        const float wt_own = e * __builtin_amdgcn_rcpf(den);

        const bool any = (__ballot(surv) != 0ull);

        float a0 = 0.f, a1 = 0.f;
        if (!any) {
            const unsigned* base = (const unsigned*)(ne_b + (size_t)b * NG * NE);
            for (int n = 0; n < NG; ++n) {
                const unsigned u = base[n * 64 + lane];
                a0 += bflo(u); a1 += bfhi(u);
            }
            const float invG = 1.f / NG;
            a0 *= invG; a1 *= invG;
        } else {
#pragma unroll
            for (int s = 0; s < NS; ++s) {
                const float wt = __shfl(wt_own, s);   // 0 for dropped entries
                a0 += wt * bflo(urow[s]);
                a1 += wt * bfhi(urow[s]);
            }
        }
        solu_b[(size_t)(b * NG + gbase + r) * 64 + lane] =
            (unsigned)f2bf(a0) | ((unsigned)f2bf(a1) << 16);
    }
}

// ---------------- Kernel D: fused GRU via MFMA (64-row tiles) ----------------
// h staged twice: bf16 (MFMA A-operand) + f32 (exact z*h blend).
__global__ __launch_bounds__(512) void gru_mfma(
        const ushort* __restrict__ x_b,
        const float* __restrict__ h_in,
        const ushort* __restrict__ wih_b, const ushort* __restrict__ whh_b,
        const float* __restrict__ bih, const float* __restrict__ bhh,
        float* __restrict__ out0, float* __restrict__ out1) {
    __shared__ __align__(16) ushort X[64 * 128];
    __shared__ __align__(16) ushort H[64 * 128];
    __shared__ __align__(16) float Hf[64 * 128];
    const int tid = threadIdx.x;
    const int rowbase = blockIdx.x * 64;

    {
#pragma unroll
        for (int i2 = 0; i2 < 2; ++i2) {
            const int i = tid + i2 * 512;
            const int r = i >> 4, kc = i & 15;
            us8 xv = *(const us8*)&x_b[(size_t)(rowbase + r) * NE + kc * 8];
            *(us8*)&X[(r * 16 + (kc ^ (r & 7))) * 8] = xv;
            const float4* h4 = (const float4*)(h_in + (size_t)(rowbase + r) * NE);
            const float4 f0 = h4[kc * 2], f1 = h4[kc * 2 + 1];
            ((float4*)Hf)[r * 32 + kc * 2]     = f0;
            ((float4*)Hf)[r * 32 + kc * 2 + 1] = f1;
            us8 hv;
            hv[0] = f2bf(f0.x); hv[1] = f2bf(f0.y); hv[2] = f2bf(f0.z); hv[3] = f2bf(f0.w);
            hv[4] = f2bf(f1.x); hv[5] = f2bf(f1.y); hv[6] = f2bf(f1.z); hv[7] = f2bf(f1.w);
            *(us8*)&H[(r * 16 + (kc ^ (r & 7))) * 8] = hv;
        }
    }
    __syncthreads();

    const int w = tid >> 6, l = tid & 63;
    const int lr = l & 15, lg = l >> 4;
    const int j = w * 16 + lr;

    f32x4 acc[4][6] = {};
#pragma unroll
    for (int ks = 0; ks < 4; ++ks) {
        bf16x8 bb[6];
#pragma unroll
        for (int g = 0; g < 3; ++g) {
            bb[g]     = *(const bf16x8*)&wih_b[(size_t)(g * 128 + j) * 128 + ks * 32 + lg * 8];
            bb[g + 3] = *(const bf16x8*)&whh_b[(size_t)(g * 128 + j) * 128 + ks * 32 + lg * 8];
        }
#pragma unroll
        for (int mf = 0; mf < 4; ++mf) {
            const int r = mf * 16 + lr;
            const int c = (r * 16 + ((ks * 4 + lg) ^ (r & 7))) * 8;
            const bf16x8 ax = *(const bf16x8*)&X[c];
            const bf16x8 ah = *(const bf16x8*)&H[c];
#pragma unroll
            for (int g = 0; g < 3; ++g) {
                acc[mf][g]     = __builtin_amdgcn_mfma_f32_16x16x32_bf16(ax, bb[g],     acc[mf][g],     0, 0, 0);
                acc[mf][g + 3] = __builtin_amdgcn_mfma_f32_16x16x32_bf16(ah, bb[g + 3], acc[mf][g + 3], 0, 0, 0);
            }
        }
    }

    const float bi0 = bih[j], bi1 = bih[128 + j], bi2 = bih[256 + j];
    const float bh0 = bhh[j], bh1 = bhh[128 + j], bh2 = bhh[256 + j];
#pragma unroll
    for (int mf = 0; mf < 4; ++mf) {
#pragma unroll
        for (int q = 0; q < 4; ++q) {
            const int rloc = mf * 16 + lg * 4 + q;
            const int row = rowbase + rloc;
            const float ir = acc[mf][0][q] + bi0;
            const float iz = acc[mf][1][q] + bi1;
            const float in_ = acc[mf][2][q] + bi2;
            const float hr = acc[mf][3][q] + bh0;
            const float hz = acc[mf][4][q] + bh1;
            const float hn = acc[mf][5][q] + bh2;
            const float rr = 1.f / (1.f + expf(-(ir + hr)));
            const float zz = 1.f / (1.f + expf(-(iz + hz)));
            const float nn = tanhf(in_ + rr * hn);
            const float hv = Hf[rloc * NE + j];
            const float nv = (1.f - zz) * nn + zz * hv;
            const size_t o = (size_t)row * NE + j;
            out1[o] = nv;
            out0[o] = (nv > 0.f) ? nv : expm1f(nv);
        }
    }
}

extern "C" void kernel_launch(void* const* d_in, const int* in_sizes, int n_in,
                              void* d_out, int out_size, void* d_ws, size_t ws_size,
                              hipStream_t stream) {
    const float* ne    = (const float*)d_in[0];
    const int*   sol   = (const int*)d_in[1];
    const float* costs = (const float*)d_in[2];
    const float* dist  = (const float*)d_in[3];
    const float* old_h = (const float*)d_in[4];
    const float* Wq    = (const float*)d_in[5];
    const float* Wk    = (const float*)d_in[6];
    const float* m1w   = (const float*)d_in[7];
    const float* m1b   = (const float*)d_in[8];
    const float* m2w   = (const float*)d_in[9];
    const float* m2b   = (const float*)d_in[10];
    const float* nhw   = (const float*)d_in[11];
    const float* wih   = (const float*)d_in[12];
    const float* whh   = (const float*)d_in[13];
    const float* bih   = (const float*)d_in[14];
    const float* bhh   = (const float*)d_in[15];

    float* out0 = (float*)d_out;
    float* out1 = out0 + (size_t)NB * NG * NE;

    // workspace layout (16B aligned)
    ushort*   QKb       = (ushort*)d_ws;                               // 16.384 MB
    ushort*   ne_b      = QKb + (size_t)NB * NG * 256;                 // 8.192 MB
    int2*     edge_pack = (int2*)(ne_b + (size_t)NB * NG * NE);        // 2.56 MB
    unsigned* solu_b    = (unsigned*)(edge_pack + (size_t)NS * NB * NG);// 8.192 MB
    ushort*   wih_b     = (ushort*)(solu_b + (size_t)NB * NG * 64);    // 96 KB
    ushort*   whh_b     = wih_b + 384 * 128;                           // 96 KB

    qk_prep<<<250 + 625 + 24, 512, 0, stream>>>(
        ne, sol, dist, Wq, Wk, wih, whh,
        QKb, ne_b, edge_pack, wih_b, whh_b);
    score_agg<<<4000, 256, 0, stream>>>(
        edge_pack, costs, QKb, ne_b, m1w, m1b, m2w, m2b, nhw, solu_b);
    gru_mfma<<<(NB * NG) / 64, 512, 0, stream>>>(
        (const ushort*)solu_b, old_h, wih_b, whh_b, bih, bhh, out0, out1);
}